// Round 1
// baseline (928.728 us; speedup 1.0000x reference)
//
#include <hip/hip_runtime.h>
#include <stdint.h>

typedef short bf16x8 __attribute__((ext_vector_type(8)));
typedef float f32x4 __attribute__((ext_vector_type(4)));

__device__ __forceinline__ float bf2f(uint16_t b){
  union { uint32_t u; float f; } v; v.u = ((uint32_t)b) << 16; return v.f;
}
__device__ __forceinline__ uint16_t f2bf(float f){
  union { float f; uint32_t u; } v; v.f = f;
  uint32_t u = v.u;
  return (uint16_t)((u + 0x7FFFu + ((u >> 16) & 1u)) >> 16);
}

#define LDT 40  // padded LDS stride (bf16 elems): 80B rows, 16B-aligned

// ---------------- weight transpose + f32->bf16 convert ----------------
// src: (K x N) f32 row-major  ->  dst: (N x K) bf16 row-major
__global__ __launch_bounds__(256) void transpose_cvt(
    const float* __restrict__ src, uint16_t* __restrict__ dst, int K, int N)
{
  __shared__ float tile[32][33];
  int n0 = blockIdx.x * 32, k0 = blockIdx.y * 32;
  int tx = threadIdx.x & 31, ty = threadIdx.x >> 5;  // ty 0..7
  #pragma unroll
  for (int i = 0; i < 4; i++)
    tile[ty + 8*i][tx] = src[(size_t)(k0 + ty + 8*i) * N + n0 + tx];
  __syncthreads();
  #pragma unroll
  for (int i = 0; i < 4; i++)
    dst[(size_t)(n0 + ty + 8*i) * K + k0 + tx] = f2bf(tile[tx][ty + 8*i]);
}

// ---------------- K1: qkv = x @ W_qkv + b_qkv (bf16 MFMA) ----------------
// X: (M x 128) f32, WT: (384 x 128) bf16, QKV out: (M x 384) bf16
__global__ __launch_bounds__(256) void qkv_gemm(
    const float* __restrict__ X, const uint16_t* __restrict__ WT,
    const float* __restrict__ bias, uint16_t* __restrict__ QKV)
{
  __shared__ uint16_t As[128 * LDT];
  __shared__ uint16_t Bs[128 * LDT];
  int t = threadIdx.x;
  int lane = t & 63, wave = t >> 6;
  int wm = wave >> 1, wn = wave & 1;
  size_t m0 = (size_t)blockIdx.x * 128;
  int n0 = blockIdx.y * 128;

  f32x4 acc[4][4] = {};
  for (int k0 = 0; k0 < 128; k0 += 32) {
    __syncthreads();
    { // stage A (f32 -> bf16): row = t/2, 16 elems at (t&1)*16
      int row = t >> 1, c = (t & 1) * 16;
      const float* g = X + (size_t)(m0 + row) * 128 + k0 + c;
      f32x4 v0 = *(const f32x4*)(g + 0);
      f32x4 v1 = *(const f32x4*)(g + 4);
      f32x4 v2 = *(const f32x4*)(g + 8);
      f32x4 v3 = *(const f32x4*)(g + 12);
      bf16x8 o0, o1;
      #pragma unroll
      for (int j = 0; j < 4; j++) {
        o0[j]   = (short)f2bf(v0[j]); o0[4+j] = (short)f2bf(v1[j]);
        o1[j]   = (short)f2bf(v2[j]); o1[4+j] = (short)f2bf(v3[j]);
      }
      uint16_t* s = As + row * LDT + c;
      *(bf16x8*)s = o0;  *(bf16x8*)(s + 8) = o1;
    }
    { // stage B: row = t/2, 16 bf16
      int row = t >> 1, c = (t & 1) * 16;
      const uint16_t* g = WT + (size_t)(n0 + row) * 128 + k0 + c;
      uint16_t* s = Bs + row * LDT + c;
      *(bf16x8*)s       = *(const bf16x8*)g;
      *(bf16x8*)(s + 8) = *(const bf16x8*)(g + 8);
    }
    __syncthreads();
    int lr = lane & 15, lh = lane >> 4;
    bf16x8 af[4], bfr[4];
    #pragma unroll
    for (int i = 0; i < 4; i++) {
      af[i]  = *(const bf16x8*)(As + (wm*64 + i*16 + lr) * LDT + lh*8);
      bfr[i] = *(const bf16x8*)(Bs + (wn*64 + i*16 + lr) * LDT + lh*8);
    }
    #pragma unroll
    for (int i = 0; i < 4; i++)
      #pragma unroll
      for (int j = 0; j < 4; j++)
        acc[i][j] = __builtin_amdgcn_mfma_f32_16x16x32_bf16(af[i], bfr[j], acc[i][j], 0, 0, 0);
  }
  int lr = lane & 15, lh = lane >> 4;
  #pragma unroll
  for (int i = 0; i < 4; i++)
    #pragma unroll
    for (int j = 0; j < 4; j++) {
      int col = n0 + wn*64 + j*16 + lr;
      float bv = bias[col];
      #pragma unroll
      for (int r = 0; r < 4; r++) {
        size_t row = m0 + wm*64 + i*16 + lh*4 + r;
        QKV[row * 384 + col] = f2bf(acc[i][j][r] + bv);
      }
    }
}

// ---------------- K2: per-b attention (6x6, no softmax) + LN1 ----------------
// QKV: (M x 384) bf16; X: (M x 128) f32; outputs: Nmat (M x 256) bf16, AR (M x 128) bf16
__global__ __launch_bounds__(256) void attn_ln1(
    const uint16_t* __restrict__ QKV, const float* __restrict__ X,
    const float* __restrict__ g1, const float* __restrict__ be1,
    uint16_t* __restrict__ Nmat, uint16_t* __restrict__ AR)
{
  __shared__ uint16_t qs[48 * 384];   // 36864 B (Q region reused for ar)
  __shared__ float    xs[48 * 128];   // 24576 B
  __shared__ float    sb[8 * 36];     // 1152 B
  int t = threadIdx.x;
  size_t r0 = (size_t)blockIdx.x * 48;   // 8 b's -> 48 rows

  for (int i = t; i < 2304; i += 256)
    *(bf16x8*)(qs + i*8) = *(const bf16x8*)(QKV + r0*384 + (size_t)i*8);
  for (int i = t; i < 1536; i += 256)
    *(f32x4*)(xs + i*4) = *(const f32x4*)(X + r0*128 + (size_t)i*4);
  __syncthreads();

  // S[b][q][k] = Q_row(q) . K_row(k)
  for (int i = t; i < 288; i += 256) {
    int b = i / 36, q = (i / 6) % 6, k = i % 6;
    const uint16_t* Qr = qs + (b*6 + q) * 384;
    const uint16_t* Kr = qs + (b*6 + k) * 384 + 128;
    float s = 0.f;
    #pragma unroll 8
    for (int d = 0; d < 128; d++) s += bf2f(Qr[d]) * bf2f(Kr[d]);
    sb[b*36 + q*6 + k] = s;
  }
  __syncthreads();

  // ar[b][q][d] = sum_k S * V[k][d]; write bf16 into dead Q region (cols 0..127)
  for (int i = t; i < 6144; i += 256) {
    int b = i / 768, rem = i % 768, q = rem >> 7, d = rem & 127;
    float a = 0.f;
    #pragma unroll
    for (int k = 0; k < 6; k++)
      a += sb[b*36 + q*6 + k] * bf2f(qs[(b*6 + k)*384 + 256 + d]);
    qs[(b*6 + q)*384 + d] = f2bf(a);
  }
  __syncthreads();

  // LN1 over m = [x(128), ar(128)]; 48 rows x 4 lanes each
  if (t < 192) {
    int r = t >> 2, p = t & 3;
    size_t row = r0 + r;
    float s1 = 0.f, s2 = 0.f;
    if (p < 2) {
      const float* xr = xs + r*128 + p*64;
      for (int j = 0; j < 64; j++) { float v = xr[j]; s1 += v; s2 += v*v; }
    } else {
      const uint16_t* ar = qs + r*384 + (p-2)*64;
      for (int j = 0; j < 64; j++) { float v = bf2f(ar[j]); s1 += v; s2 += v*v; }
    }
    s1 += __shfl_xor(s1, 1); s2 += __shfl_xor(s2, 1);
    s1 += __shfl_xor(s1, 2); s2 += __shfl_xor(s2, 2);
    float mu = s1 * (1.f/256.f);
    float var = s2 * (1.f/256.f) - mu*mu;
    float rs = rsqrtf(var + 1e-5f);
    int j0 = p * 64;
    uint16_t* nr = Nmat + row*256 + j0;
    if (p < 2) {
      const float* xr = xs + r*128 + j0;
      for (int j = 0; j < 64; j++)
        nr[j] = f2bf((xr[j] - mu) * rs * g1[j0+j] + be1[j0+j]);
    } else {
      const uint16_t* ar = qs + r*384 + (j0 - 128);
      for (int j = 0; j < 64; j++)
        nr[j] = f2bf((bf2f(ar[j]) - mu) * rs * g1[j0+j] + be1[j0+j]);
      // also persist ar to global (needed by LN2 / f concat)
      uint16_t* arg = AR + row*128 + (j0 - 128);
      for (int j = 0; j < 64; j++) arg[j] = ar[j];
    }
  }
}

// ---------------- K3: h = n @ W_fp + b_fp, then LN2 over [h,x,ar] -> f bf16 ----------------
// Nmat: (M x 256) bf16; WfpT: (256 x 256) bf16; F out: (M x 512) bf16
__global__ __launch_bounds__(256) void fp_ln2(
    const uint16_t* __restrict__ Nmat, const uint16_t* __restrict__ WfpT,
    const float* __restrict__ b_fp, const float* __restrict__ X,
    const uint16_t* __restrict__ AR, const float* __restrict__ g2,
    const float* __restrict__ be2, uint16_t* __restrict__ F)
{
  __shared__ uint16_t As[64 * LDT];     // 5120 B
  __shared__ uint16_t Bs[256 * LDT];    // 20480 B
  __shared__ uint16_t hs[64][256];      // 32768 B
  int t = threadIdx.x;
  int lane = t & 63, wave = t >> 6;
  size_t m0 = (size_t)blockIdx.x * 64;

  f32x4 acc[4][4] = {};
  for (int k0 = 0; k0 < 256; k0 += 32) {
    __syncthreads();
    { // A: 64x32
      int row = t >> 2, c = (t & 3) * 8;
      *(bf16x8*)(As + row*LDT + c) =
          *(const bf16x8*)(Nmat + (m0 + row)*256 + k0 + c);
    }
    { // B: 256x32 (row = t)
      const uint16_t* g = WfpT + (size_t)t * 256 + k0;
      uint16_t* s = Bs + t * LDT;
      #pragma unroll
      for (int j = 0; j < 4; j++)
        *(bf16x8*)(s + j*8) = *(const bf16x8*)(g + j*8);
    }
    __syncthreads();
    int lr = lane & 15, lh = lane >> 4;
    bf16x8 af[4], bfr[4];
    #pragma unroll
    for (int i = 0; i < 4; i++) {
      af[i]  = *(const bf16x8*)(As + (i*16 + lr) * LDT + lh*8);
      bfr[i] = *(const bf16x8*)(Bs + (wave*64 + i*16 + lr) * LDT + lh*8);
    }
    #pragma unroll
    for (int i = 0; i < 4; i++)
      #pragma unroll
      for (int j = 0; j < 4; j++)
        acc[i][j] = __builtin_amdgcn_mfma_f32_16x16x32_bf16(af[i], bfr[j], acc[i][j], 0, 0, 0);
  }
  { // h (+bias) -> LDS bf16
    int lr = lane & 15, lh = lane >> 4;
    #pragma unroll
    for (int i = 0; i < 4; i++)
      #pragma unroll
      for (int j = 0; j < 4; j++) {
        int col = wave*64 + j*16 + lr;
        float bv = b_fp[col];
        #pragma unroll
        for (int r = 0; r < 4; r++)
          hs[i*16 + lh*4 + r][col] = f2bf(acc[i][j][r] + bv);
      }
  }
  __syncthreads();
  // LN2: 64 rows x 4 lanes; row = [h(256) | x(128) | ar(128)]
  {
    int r = t >> 2, p = t & 3;
    size_t row = m0 + r;
    float s1 = 0.f, s2 = 0.f;
    if (p < 2) {
      const uint16_t* h = &hs[r][p*128];
      for (int j = 0; j < 128; j++) { float v = bf2f(h[j]); s1 += v; s2 += v*v; }
    } else if (p == 2) {
      const float* xr = X + row * 128;
      for (int j = 0; j < 128; j++) { float v = xr[j]; s1 += v; s2 += v*v; }
    } else {
      const uint16_t* ar = AR + row * 128;
      for (int j = 0; j < 128; j++) { float v = bf2f(ar[j]); s1 += v; s2 += v*v; }
    }
    s1 += __shfl_xor(s1, 1); s2 += __shfl_xor(s2, 1);
    s1 += __shfl_xor(s1, 2); s2 += __shfl_xor(s2, 2);
    float mu = s1 * (1.f/512.f);
    float var = s2 * (1.f/512.f) - mu*mu;
    float rs = rsqrtf(var + 1e-5f);
    int j0 = p * 128;
    uint16_t* fr = F + row * 512 + j0;
    if (p < 2) {
      const uint16_t* h = &hs[r][j0];
      for (int j = 0; j < 128; j++)
        fr[j] = f2bf((bf2f(h[j]) - mu) * rs * g2[j0+j] + be2[j0+j]);
    } else if (p == 2) {
      const float* xr = X + row * 128;
      for (int j = 0; j < 128; j++)
        fr[j] = f2bf((xr[j] - mu) * rs * g2[j0+j] + be2[j0+j]);
    } else {
      const uint16_t* ar = AR + row * 128;
      for (int j = 0; j < 128; j++)
        fr[j] = f2bf((bf2f(ar[j]) - mu) * rs * g2[j0+j] + be2[j0+j]);
    }
  }
}

// ---------------- K4: out = relu(f @ W_s + b_s) ----------------
// F: (32768 x 3072) bf16; WsT: (1024 x 3072) bf16; OUT: (32768 x 1024) f32
__global__ __launch_bounds__(256) void out_gemm(
    const uint16_t* __restrict__ F, const uint16_t* __restrict__ WsT,
    const float* __restrict__ b_s, float* __restrict__ OUT)
{
  __shared__ uint16_t As[128 * LDT];
  __shared__ uint16_t Bs[128 * LDT];
  int t = threadIdx.x;
  int lane = t & 63, wave = t >> 6;
  int wm = wave >> 1, wn = wave & 1;
  size_t m0 = (size_t)blockIdx.x * 128;
  int n0 = blockIdx.y * 128;

  f32x4 acc[4][4] = {};
  for (int k0 = 0; k0 < 3072; k0 += 32) {
    __syncthreads();
    {
      int row = t >> 1, c = (t & 1) * 16;
      const uint16_t* g = F + (m0 + row) * 3072 + k0 + c;
      uint16_t* s = As + row * LDT + c;
      *(bf16x8*)s       = *(const bf16x8*)g;
      *(bf16x8*)(s + 8) = *(const bf16x8*)(g + 8);
    }
    {
      int row = t >> 1, c = (t & 1) * 16;
      const uint16_t* g = WsT + (size_t)(n0 + row) * 3072 + k0 + c;
      uint16_t* s = Bs + row * LDT + c;
      *(bf16x8*)s       = *(const bf16x8*)g;
      *(bf16x8*)(s + 8) = *(const bf16x8*)(g + 8);
    }
    __syncthreads();
    int lr = lane & 15, lh = lane >> 4;
    bf16x8 af[4], bfr[4];
    #pragma unroll
    for (int i = 0; i < 4; i++) {
      af[i]  = *(const bf16x8*)(As + (wm*64 + i*16 + lr) * LDT + lh*8);
      bfr[i] = *(const bf16x8*)(Bs + (wn*64 + i*16 + lr) * LDT + lh*8);
    }
    #pragma unroll
    for (int i = 0; i < 4; i++)
      #pragma unroll
      for (int j = 0; j < 4; j++)
        acc[i][j] = __builtin_amdgcn_mfma_f32_16x16x32_bf16(af[i], bfr[j], acc[i][j], 0, 0, 0);
  }
  int lr = lane & 15, lh = lane >> 4;
  #pragma unroll
  for (int i = 0; i < 4; i++)
    #pragma unroll
    for (int j = 0; j < 4; j++) {
      int col = n0 + wn*64 + j*16 + lr;
      float bv = b_s[col];
      #pragma unroll
      for (int r = 0; r < 4; r++) {
        size_t row = m0 + wm*64 + i*16 + lh*4 + r;
        OUT[row * 1024 + col] = fmaxf(acc[i][j][r] + bv, 0.f);
      }
    }
}

extern "C" void kernel_launch(void* const* d_in, const int* in_sizes, int n_in,
                              void* d_out, int out_size, void* d_ws, size_t ws_size,
                              hipStream_t stream) {
  const float* x    = (const float*)d_in[0];
  const float* Wqkv = (const float*)d_in[1];
  const float* bqkv = (const float*)d_in[2];
  const float* g1   = (const float*)d_in[3];
  const float* be1  = (const float*)d_in[4];
  const float* Wfp  = (const float*)d_in[5];
  const float* bfp  = (const float*)d_in[6];
  const float* g2   = (const float*)d_in[7];
  const float* be2  = (const float*)d_in[8];
  const float* Ws   = (const float*)d_in[9];
  const float* bs   = (const float*)d_in[10];
  float* out = (float*)d_out;

  uint8_t* ws = (uint8_t*)d_ws;
  // F (32768x3072 bf16, 201.3MB) overlays QKV (196608x384 bf16, 151MB):
  // QKV is dead before F is first written (K3).
  uint16_t* F     = (uint16_t*)(ws);
  uint16_t* QKV   = (uint16_t*)(ws);
  uint16_t* AR    = (uint16_t*)(ws + 201326592ull);   // 196608x128 bf16
  uint16_t* Nmat  = (uint16_t*)(ws + 251658240ull);   // 196608x256 bf16
  uint16_t* WqkvT = (uint16_t*)(ws + 352321536ull);   // 384x128 bf16
  uint16_t* WfpT  = (uint16_t*)(ws + 352419840ull);   // 256x256 bf16
  uint16_t* WsT   = (uint16_t*)(ws + 352550912ull);   // 1024x3072 bf16

  transpose_cvt<<<dim3(12, 4), 256, 0, stream>>>(Wqkv, WqkvT, 128, 384);
  transpose_cvt<<<dim3(8, 8), 256, 0, stream>>>(Wfp, WfpT, 256, 256);
  transpose_cvt<<<dim3(32, 96), 256, 0, stream>>>(Ws, WsT, 3072, 1024);
  qkv_gemm<<<dim3(1536, 3), 256, 0, stream>>>(x, WqkvT, bqkv, QKV);
  attn_ln1<<<dim3(4096), 256, 0, stream>>>(QKV, x, g1, be1, Nmat, AR);
  fp_ln2<<<dim3(3072), 256, 0, stream>>>(Nmat, WfpT, bfp, x, AR, g2, be2, F);
  out_gemm<<<dim3(256, 8), 256, 0, stream>>>(F, WsT, bs, out);
}

// Round 2
// 873.855 us; speedup vs baseline: 1.0628x; 1.0628x over previous
//
#include <hip/hip_runtime.h>
#include <stdint.h>

typedef short bf16x8 __attribute__((ext_vector_type(8)));
typedef float f32x4 __attribute__((ext_vector_type(4)));

__device__ __forceinline__ float bf2f(uint16_t b){
  union { uint32_t u; float f; } v; v.u = ((uint32_t)b) << 16; return v.f;
}
__device__ __forceinline__ uint16_t f2bf(float f){
  union { float f; uint32_t u; } v; v.f = f;
  uint32_t u = v.u;
  return (uint16_t)((u + 0x7FFFu + ((u >> 16) & 1u)) >> 16);
}

// async global->LDS, 16B per lane; lds base must be wave-uniform (HW adds lane*16)
__device__ __forceinline__ void gl2lds16(const uint16_t* g, uint16_t* l) {
  __builtin_amdgcn_global_load_lds((const __attribute__((address_space(1))) void*)g,
                                   (__attribute__((address_space(3))) void*)l, 16, 0, 0);
}

#define LDT 40  // padded LDS stride for reg-staged kernels

// ---------------- weight transpose + f32->bf16 convert ----------------
__global__ __launch_bounds__(256) void transpose_cvt(
    const float* __restrict__ src, uint16_t* __restrict__ dst, int K, int N)
{
  __shared__ float tile[32][33];
  int n0 = blockIdx.x * 32, k0 = blockIdx.y * 32;
  int tx = threadIdx.x & 31, ty = threadIdx.x >> 5;
  #pragma unroll
  for (int i = 0; i < 4; i++)
    tile[ty + 8*i][tx] = src[(size_t)(k0 + ty + 8*i) * N + n0 + tx];
  __syncthreads();
  #pragma unroll
  for (int i = 0; i < 4; i++)
    dst[(size_t)(n0 + ty + 8*i) * K + k0 + tx] = f2bf(tile[tx][ty + 8*i]);
}

// ---------------- K1: qkv = x @ W_qkv + b_qkv (bf16 MFMA) ----------------
__global__ __launch_bounds__(256) void qkv_gemm(
    const float* __restrict__ X, const uint16_t* __restrict__ WT,
    const float* __restrict__ bias, uint16_t* __restrict__ QKV)
{
  __shared__ uint16_t As[128 * LDT];
  __shared__ uint16_t Bs[128 * LDT];
  int t = threadIdx.x;
  int lane = t & 63, wave = t >> 6;
  int wm = wave >> 1, wn = wave & 1;
  size_t m0 = (size_t)blockIdx.x * 128;
  int n0 = blockIdx.y * 128;

  f32x4 acc[4][4] = {};
  for (int k0 = 0; k0 < 128; k0 += 32) {
    __syncthreads();
    { // stage A (f32 -> bf16)
      int row = t >> 1, c = (t & 1) * 16;
      const float* g = X + (size_t)(m0 + row) * 128 + k0 + c;
      f32x4 v0 = *(const f32x4*)(g + 0);
      f32x4 v1 = *(const f32x4*)(g + 4);
      f32x4 v2 = *(const f32x4*)(g + 8);
      f32x4 v3 = *(const f32x4*)(g + 12);
      bf16x8 o0, o1;
      #pragma unroll
      for (int j = 0; j < 4; j++) {
        o0[j]   = (short)f2bf(v0[j]); o0[4+j] = (short)f2bf(v1[j]);
        o1[j]   = (short)f2bf(v2[j]); o1[4+j] = (short)f2bf(v3[j]);
      }
      uint16_t* s = As + row * LDT + c;
      *(bf16x8*)s = o0;  *(bf16x8*)(s + 8) = o1;
    }
    { // stage B
      int row = t >> 1, c = (t & 1) * 16;
      const uint16_t* g = WT + (size_t)(n0 + row) * 128 + k0 + c;
      uint16_t* s = Bs + row * LDT + c;
      *(bf16x8*)s       = *(const bf16x8*)g;
      *(bf16x8*)(s + 8) = *(const bf16x8*)(g + 8);
    }
    __syncthreads();
    int lr = lane & 15, lh = lane >> 4;
    bf16x8 af[4], bfr[4];
    #pragma unroll
    for (int i = 0; i < 4; i++) {
      af[i]  = *(const bf16x8*)(As + (wm*64 + i*16 + lr) * LDT + lh*8);
      bfr[i] = *(const bf16x8*)(Bs + (wn*64 + i*16 + lr) * LDT + lh*8);
    }
    #pragma unroll
    for (int i = 0; i < 4; i++)
      #pragma unroll
      for (int j = 0; j < 4; j++)
        acc[i][j] = __builtin_amdgcn_mfma_f32_16x16x32_bf16(af[i], bfr[j], acc[i][j], 0, 0, 0);
  }
  int lr = lane & 15, lh = lane >> 4;
  #pragma unroll
  for (int i = 0; i < 4; i++)
    #pragma unroll
    for (int j = 0; j < 4; j++) {
      int col = n0 + wn*64 + j*16 + lr;
      float bv = bias[col];
      #pragma unroll
      for (int r = 0; r < 4; r++) {
        size_t row = m0 + wm*64 + i*16 + lh*4 + r;
        QKV[row * 384 + col] = f2bf(acc[i][j][r] + bv);
      }
    }
}

// ---------------- K2: per-b attention (6x6, no softmax) + LN1 ----------------
__global__ __launch_bounds__(256) void attn_ln1(
    const uint16_t* __restrict__ QKV, const float* __restrict__ X,
    const float* __restrict__ g1, const float* __restrict__ be1,
    uint16_t* __restrict__ Nmat, uint16_t* __restrict__ AR)
{
  __shared__ uint16_t qs[48 * 384];
  __shared__ float    xs[48 * 128];
  __shared__ float    sb[8 * 36];
  int t = threadIdx.x;
  size_t r0 = (size_t)blockIdx.x * 48;

  for (int i = t; i < 2304; i += 256)
    *(bf16x8*)(qs + i*8) = *(const bf16x8*)(QKV + r0*384 + (size_t)i*8);
  for (int i = t; i < 1536; i += 256)
    *(f32x4*)(xs + i*4) = *(const f32x4*)(X + r0*128 + (size_t)i*4);
  __syncthreads();

  for (int i = t; i < 288; i += 256) {
    int b = i / 36, q = (i / 6) % 6, k = i % 6;
    const uint16_t* Qr = qs + (b*6 + q) * 384;
    const uint16_t* Kr = qs + (b*6 + k) * 384 + 128;
    float s = 0.f;
    #pragma unroll 8
    for (int d = 0; d < 128; d++) s += bf2f(Qr[d]) * bf2f(Kr[d]);
    sb[b*36 + q*6 + k] = s;
  }
  __syncthreads();

  for (int i = t; i < 6144; i += 256) {
    int b = i / 768, rem = i % 768, q = rem >> 7, d = rem & 127;
    float a = 0.f;
    #pragma unroll
    for (int k = 0; k < 6; k++)
      a += sb[b*36 + q*6 + k] * bf2f(qs[(b*6 + k)*384 + 256 + d]);
    qs[(b*6 + q)*384 + d] = f2bf(a);
  }
  __syncthreads();

  if (t < 192) {
    int r = t >> 2, p = t & 3;
    size_t row = r0 + r;
    float s1 = 0.f, s2 = 0.f;
    if (p < 2) {
      const float* xr = xs + r*128 + p*64;
      for (int j = 0; j < 64; j++) { float v = xr[j]; s1 += v; s2 += v*v; }
    } else {
      const uint16_t* ar = qs + r*384 + (p-2)*64;
      for (int j = 0; j < 64; j++) { float v = bf2f(ar[j]); s1 += v; s2 += v*v; }
    }
    s1 += __shfl_xor(s1, 1); s2 += __shfl_xor(s2, 1);
    s1 += __shfl_xor(s1, 2); s2 += __shfl_xor(s2, 2);
    float mu = s1 * (1.f/256.f);
    float var = s2 * (1.f/256.f) - mu*mu;
    float rs = rsqrtf(var + 1e-5f);
    int j0 = p * 64;
    uint16_t* nr = Nmat + row*256 + j0;
    if (p < 2) {
      const float* xr = xs + r*128 + j0;
      for (int j = 0; j < 64; j++)
        nr[j] = f2bf((xr[j] - mu) * rs * g1[j0+j] + be1[j0+j]);
    } else {
      const uint16_t* ar = qs + r*384 + (j0 - 128);
      for (int j = 0; j < 64; j++)
        nr[j] = f2bf((bf2f(ar[j]) - mu) * rs * g1[j0+j] + be1[j0+j]);
      uint16_t* arg = AR + row*128 + (j0 - 128);
      for (int j = 0; j < 64; j++) arg[j] = ar[j];
    }
  }
}

// ---------------- K3: h = n @ W_fp + b_fp, then LN2 -> f bf16 ----------------
// gload_lds staging, linear LDS
__global__ __launch_bounds__(256) void fp_ln2(
    const uint16_t* __restrict__ Nmat, const uint16_t* __restrict__ WfpT,
    const float* __restrict__ b_fp, const float* __restrict__ X,
    const uint16_t* __restrict__ AR, const float* __restrict__ g2,
    const float* __restrict__ be2, uint16_t* __restrict__ F)
{
  __shared__ uint16_t As[64 * 32];      // 4 KB linear
  __shared__ uint16_t Bs[256 * 32];     // 16 KB linear
  __shared__ uint16_t hs[64][256];      // 32 KB
  int t = threadIdx.x;
  int lane = t & 63, wave = t >> 6;
  size_t m0 = (size_t)blockIdx.x * 64;

  int r_sub = (wave << 4) + (lane >> 2);   // 0..63
  int c_sub = (lane & 3) * 8;
  const uint16_t* Ag = Nmat + (m0 + r_sub) * 256 + c_sub;
  const uint16_t* Bg = WfpT + (size_t)r_sub * 256 + c_sub;
  uint16_t* lA = As + wave * 512;

  f32x4 acc[4][4] = {};
  for (int k0 = 0; k0 < 256; k0 += 32) {
    __syncthreads();
    gl2lds16(Ag + k0, lA);
    #pragma unroll
    for (int s = 0; s < 4; s++)
      gl2lds16(Bg + (size_t)s * 64 * 256 + k0, Bs + s * 2048 + wave * 512);
    __syncthreads();
    int lr = lane & 15, lh = lane >> 4;
    bf16x8 af[4], bfr[4];
    #pragma unroll
    for (int i = 0; i < 4; i++) {
      af[i]  = *(const bf16x8*)(As + (i*16 + lr) * 32 + lh*8);
      bfr[i] = *(const bf16x8*)(Bs + (wave*64 + i*16 + lr) * 32 + lh*8);
    }
    #pragma unroll
    for (int i = 0; i < 4; i++)
      #pragma unroll
      for (int j = 0; j < 4; j++)
        acc[i][j] = __builtin_amdgcn_mfma_f32_16x16x32_bf16(af[i], bfr[j], acc[i][j], 0, 0, 0);
  }
  {
    int lr = lane & 15, lh = lane >> 4;
    #pragma unroll
    for (int i = 0; i < 4; i++)
      #pragma unroll
      for (int j = 0; j < 4; j++) {
        int col = wave*64 + j*16 + lr;
        float bv = b_fp[col];
        #pragma unroll
        for (int r = 0; r < 4; r++)
          hs[i*16 + lh*4 + r][col] = f2bf(acc[i][j][r] + bv);
      }
  }
  __syncthreads();
  {
    int r = t >> 2, p = t & 3;
    size_t row = m0 + r;
    float s1 = 0.f, s2 = 0.f;
    if (p < 2) {
      const uint16_t* h = &hs[r][p*128];
      for (int j = 0; j < 128; j++) { float v = bf2f(h[j]); s1 += v; s2 += v*v; }
    } else if (p == 2) {
      const float* xr = X + row * 128;
      for (int j = 0; j < 128; j++) { float v = xr[j]; s1 += v; s2 += v*v; }
    } else {
      const uint16_t* ar = AR + row * 128;
      for (int j = 0; j < 128; j++) { float v = bf2f(ar[j]); s1 += v; s2 += v*v; }
    }
    s1 += __shfl_xor(s1, 1); s2 += __shfl_xor(s2, 1);
    s1 += __shfl_xor(s1, 2); s2 += __shfl_xor(s2, 2);
    float mu = s1 * (1.f/512.f);
    float var = s2 * (1.f/512.f) - mu*mu;
    float rs = rsqrtf(var + 1e-5f);
    int j0 = p * 128;
    uint16_t* fr = F + row * 512 + j0;
    if (p < 2) {
      const uint16_t* h = &hs[r][j0];
      for (int j = 0; j < 128; j++)
        fr[j] = f2bf((bf2f(h[j]) - mu) * rs * g2[j0+j] + be2[j0+j]);
    } else if (p == 2) {
      const float* xr = X + row * 128;
      for (int j = 0; j < 128; j++)
        fr[j] = f2bf((xr[j] - mu) * rs * g2[j0+j] + be2[j0+j]);
    } else {
      const uint16_t* ar = AR + row * 128;
      for (int j = 0; j < 128; j++)
        fr[j] = f2bf((bf2f(ar[j]) - mu) * rs * g2[j0+j] + be2[j0+j]);
    }
  }
}

// ---------------- K4: out = relu(f @ W_s + b_s) ----------------
// gload_lds staging, linear LDS, XCD-chunked swizzle (N-fastest)
__global__ __launch_bounds__(256) void out_gemm(
    const uint16_t* __restrict__ F, const uint16_t* __restrict__ WsT,
    const float* __restrict__ b_s, float* __restrict__ OUT)
{
  __shared__ uint16_t As[128 * 32];   // 8 KB linear
  __shared__ uint16_t Bs[128 * 32];   // 8 KB linear
  int t = threadIdx.x;
  int lane = t & 63, wave = t >> 6;
  int wm = wave >> 1, wn = wave & 1;

  // 2048 blocks; XCD k (bid%8) gets contiguous logical chunk; n fastest
  int bid = blockIdx.x;
  int swz = (bid & 7) * 256 + (bid >> 3);
  size_t m0 = (size_t)(swz >> 3) * 128;
  int n0 = (swz & 7) * 128;

  int r_sub = (wave << 4) + (lane >> 2);   // 0..63
  int c_sub = (lane & 3) * 8;
  const uint16_t* Ag = F   + (m0 + r_sub) * 3072 + c_sub;
  const uint16_t* Bg = WsT + (size_t)(n0 + r_sub) * 3072 + c_sub;
  uint16_t* lA0 = As + wave * 512;
  uint16_t* lA1 = As + 2048 + wave * 512;
  uint16_t* lB0 = Bs + wave * 512;
  uint16_t* lB1 = Bs + 2048 + wave * 512;

  f32x4 acc[4][4] = {};
  for (int k0 = 0; k0 < 3072; k0 += 32) {
    __syncthreads();
    gl2lds16(Ag + k0, lA0);
    gl2lds16(Ag + (size_t)64 * 3072 + k0, lA1);
    gl2lds16(Bg + k0, lB0);
    gl2lds16(Bg + (size_t)64 * 3072 + k0, lB1);
    __syncthreads();
    int lr = lane & 15, lh = lane >> 4;
    bf16x8 af[4], bfr[4];
    #pragma unroll
    for (int i = 0; i < 4; i++) {
      af[i]  = *(const bf16x8*)(As + (wm*64 + i*16 + lr) * 32 + lh*8);
      bfr[i] = *(const bf16x8*)(Bs + (wn*64 + i*16 + lr) * 32 + lh*8);
    }
    #pragma unroll
    for (int i = 0; i < 4; i++)
      #pragma unroll
      for (int j = 0; j < 4; j++)
        acc[i][j] = __builtin_amdgcn_mfma_f32_16x16x32_bf16(af[i], bfr[j], acc[i][j], 0, 0, 0);
  }
  int lr = lane & 15, lh = lane >> 4;
  #pragma unroll
  for (int i = 0; i < 4; i++)
    #pragma unroll
    for (int j = 0; j < 4; j++) {
      int col = n0 + wn*64 + j*16 + lr;
      float bv = b_s[col];
      #pragma unroll
      for (int r = 0; r < 4; r++) {
        size_t row = m0 + wm*64 + i*16 + lh*4 + r;
        OUT[row * 1024 + col] = fmaxf(acc[i][j][r] + bv, 0.f);
      }
    }
}

extern "C" void kernel_launch(void* const* d_in, const int* in_sizes, int n_in,
                              void* d_out, int out_size, void* d_ws, size_t ws_size,
                              hipStream_t stream) {
  const float* x    = (const float*)d_in[0];
  const float* Wqkv = (const float*)d_in[1];
  const float* bqkv = (const float*)d_in[2];
  const float* g1   = (const float*)d_in[3];
  const float* be1  = (const float*)d_in[4];
  const float* Wfp  = (const float*)d_in[5];
  const float* bfp  = (const float*)d_in[6];
  const float* g2   = (const float*)d_in[7];
  const float* be2  = (const float*)d_in[8];
  const float* Ws   = (const float*)d_in[9];
  const float* bs   = (const float*)d_in[10];
  float* out = (float*)d_out;

  uint8_t* ws = (uint8_t*)d_ws;
  uint16_t* F     = (uint16_t*)(ws);                  // overlays QKV (dead by K3)
  uint16_t* QKV   = (uint16_t*)(ws);
  uint16_t* AR    = (uint16_t*)(ws + 201326592ull);
  uint16_t* Nmat  = (uint16_t*)(ws + 251658240ull);
  uint16_t* WqkvT = (uint16_t*)(ws + 352321536ull);
  uint16_t* WfpT  = (uint16_t*)(ws + 352419840ull);
  uint16_t* WsT   = (uint16_t*)(ws + 352550912ull);

  transpose_cvt<<<dim3(12, 4), 256, 0, stream>>>(Wqkv, WqkvT, 128, 384);
  transpose_cvt<<<dim3(8, 8), 256, 0, stream>>>(Wfp, WfpT, 256, 256);
  transpose_cvt<<<dim3(32, 96), 256, 0, stream>>>(Ws, WsT, 3072, 1024);
  qkv_gemm<<<dim3(1536, 3), 256, 0, stream>>>(x, WqkvT, bqkv, QKV);
  attn_ln1<<<dim3(4096), 256, 0, stream>>>(QKV, x, g1, be1, Nmat, AR);
  fp_ln2<<<dim3(3072), 256, 0, stream>>>(Nmat, WfpT, bfp, x, AR, g2, be2, F);
  out_gemm<<<dim3(2048), 256, 0, stream>>>(F, WsT, bs, out);
}

// Round 3
// 738.925 us; speedup vs baseline: 1.2569x; 1.1826x over previous
//
#include <hip/hip_runtime.h>
#include <stdint.h>

typedef short bf16x8 __attribute__((ext_vector_type(8)));
typedef float f32x4 __attribute__((ext_vector_type(4)));

__device__ __forceinline__ float bf2f(uint16_t b){
  union { uint32_t u; float f; } v; v.u = ((uint32_t)b) << 16; return v.f;
}
__device__ __forceinline__ float u2f(uint32_t u){
  union { uint32_t u; float f; } v; v.u = u; return v.f;
}
__device__ __forceinline__ uint16_t f2bf(float f){
  union { float f; uint32_t u; } v; v.f = f;
  uint32_t u = v.u;
  return (uint16_t)((u + 0x7FFFu + ((u >> 16) & 1u)) >> 16);
}

// async global->LDS, 16B per lane; lds base wave-uniform (HW adds lane*16)
__device__ __forceinline__ void gl2lds16(const uint16_t* g, uint16_t* l) {
  __builtin_amdgcn_global_load_lds((const __attribute__((address_space(1))) void*)g,
                                   (__attribute__((address_space(3))) void*)l, 16, 0, 0);
}

#define LDT 40  // padded LDS stride for reg-staged qkv_gemm

// ---------------- weight transpose + f32->bf16 convert ----------------
__global__ __launch_bounds__(256) void transpose_cvt(
    const float* __restrict__ src, uint16_t* __restrict__ dst, int K, int N)
{
  __shared__ float tile[32][33];
  int n0 = blockIdx.x * 32, k0 = blockIdx.y * 32;
  int tx = threadIdx.x & 31, ty = threadIdx.x >> 5;
  #pragma unroll
  for (int i = 0; i < 4; i++)
    tile[ty + 8*i][tx] = src[(size_t)(k0 + ty + 8*i) * N + n0 + tx];
  __syncthreads();
  #pragma unroll
  for (int i = 0; i < 4; i++)
    dst[(size_t)(n0 + ty + 8*i) * K + k0 + tx] = f2bf(tile[tx][ty + 8*i]);
}

// ---------------- K1: qkv = x @ W_qkv + b_qkv (bf16 MFMA) ----------------
__global__ __launch_bounds__(256) void qkv_gemm(
    const float* __restrict__ X, const uint16_t* __restrict__ WT,
    const float* __restrict__ bias, uint16_t* __restrict__ QKV)
{
  __shared__ uint16_t As[128 * LDT];
  __shared__ uint16_t Bs[128 * LDT];
  int t = threadIdx.x;
  int lane = t & 63, wave = t >> 6;
  int wm = wave >> 1, wn = wave & 1;
  size_t m0 = (size_t)blockIdx.x * 128;
  int n0 = blockIdx.y * 128;

  f32x4 acc[4][4] = {};
  for (int k0 = 0; k0 < 128; k0 += 32) {
    __syncthreads();
    { // stage A (f32 -> bf16)
      int row = t >> 1, c = (t & 1) * 16;
      const float* g = X + (size_t)(m0 + row) * 128 + k0 + c;
      f32x4 v0 = *(const f32x4*)(g + 0);
      f32x4 v1 = *(const f32x4*)(g + 4);
      f32x4 v2 = *(const f32x4*)(g + 8);
      f32x4 v3 = *(const f32x4*)(g + 12);
      bf16x8 o0, o1;
      #pragma unroll
      for (int j = 0; j < 4; j++) {
        o0[j]   = (short)f2bf(v0[j]); o0[4+j] = (short)f2bf(v1[j]);
        o1[j]   = (short)f2bf(v2[j]); o1[4+j] = (short)f2bf(v3[j]);
      }
      uint16_t* s = As + row * LDT + c;
      *(bf16x8*)s = o0;  *(bf16x8*)(s + 8) = o1;
    }
    { // stage B
      int row = t >> 1, c = (t & 1) * 16;
      const uint16_t* g = WT + (size_t)(n0 + row) * 128 + k0 + c;
      uint16_t* s = Bs + row * LDT + c;
      *(bf16x8*)s       = *(const bf16x8*)g;
      *(bf16x8*)(s + 8) = *(const bf16x8*)(g + 8);
    }
    __syncthreads();
    int lr = lane & 15, lh = lane >> 4;
    bf16x8 af[4], bfr[4];
    #pragma unroll
    for (int i = 0; i < 4; i++) {
      af[i]  = *(const bf16x8*)(As + (wm*64 + i*16 + lr) * LDT + lh*8);
      bfr[i] = *(const bf16x8*)(Bs + (wn*64 + i*16 + lr) * LDT + lh*8);
    }
    #pragma unroll
    for (int i = 0; i < 4; i++)
      #pragma unroll
      for (int j = 0; j < 4; j++)
        acc[i][j] = __builtin_amdgcn_mfma_f32_16x16x32_bf16(af[i], bfr[j], acc[i][j], 0, 0, 0);
  }
  int lr = lane & 15, lh = lane >> 4;
  #pragma unroll
  for (int i = 0; i < 4; i++)
    #pragma unroll
    for (int j = 0; j < 4; j++) {
      int col = n0 + wn*64 + j*16 + lr;
      float bv = bias[col];
      #pragma unroll
      for (int r = 0; r < 4; r++) {
        size_t row = m0 + wm*64 + i*16 + lh*4 + r;
        QKV[row * 384 + col] = f2bf(acc[i][j][r] + bv);
      }
    }
}

// ---------------- K2: per-b attention (6x6, no softmax) + LN1 ----------------
// vectorized: bf16 consumed as packed u32 pairs; padded LDS strides
#define LQ 392   // qs row stride (bf16 elems), 784B: banks spread 4r%32
#define LX 136   // xs row stride, 272B

__global__ __launch_bounds__(256) void attn_ln1(
    const uint16_t* __restrict__ QKV, const float* __restrict__ X,
    const float* __restrict__ g1, const float* __restrict__ be1,
    uint16_t* __restrict__ Nmat, uint16_t* __restrict__ AR)
{
  __shared__ uint16_t qs[48 * LQ];   // 36.8 KB ([0:128)=Q then ar, [128:256)=K, [256:384)=V)
  __shared__ uint16_t xs[48 * LX];   // 12.8 KB (x as bf16)
  __shared__ float    sb[8 * 36];
  __shared__ float    smu[48], srs[48];
  int t = threadIdx.x;
  size_t r0 = (size_t)blockIdx.x * 48;

  // stage QKV (48x384 bf16) -> qs (padded rows)
  for (int i = t; i < 2304; i += 256) {
    int row = i / 48, c = (i % 48) * 8;
    *(bf16x8*)(qs + row*LQ + c) = *(const bf16x8*)(QKV + (r0+row)*384 + c);
  }
  // stage x (48x128 f32) -> xs bf16 (padded rows)
  for (int i = t; i < 768; i += 256) {
    int row = i >> 4, c = (i & 15) * 8;
    const float* g = X + (r0+row)*128 + c;
    f32x4 v0 = *(const f32x4*)g, v1 = *(const f32x4*)(g + 4);
    bf16x8 o;
    #pragma unroll
    for (int j = 0; j < 4; j++) { o[j] = (short)f2bf(v0[j]); o[4+j] = (short)f2bf(v1[j]); }
    *(bf16x8*)(xs + row*LX + c) = o;
  }
  __syncthreads();

  // S[b][q][k] = Q_row(q) . K_row(k)   (u32-pair math)
  for (int i = t; i < 288; i += 256) {
    int b = i / 36, q = (i / 6) % 6, k = i % 6;
    const uint32_t* Qr = (const uint32_t*)(qs + (b*6 + q) * LQ);
    const uint32_t* Kr = (const uint32_t*)(qs + (b*6 + k) * LQ + 128);
    float s = 0.f;
    #pragma unroll 8
    for (int d = 0; d < 64; d++) {
      uint32_t qu = Qr[d], ku = Kr[d];
      s += u2f(qu << 16) * u2f(ku << 16) + u2f(qu & 0xFFFF0000u) * u2f(ku & 0xFFFF0000u);
    }
    sb[i] = s;   // i == b*36 + q*6 + k
  }
  __syncthreads();

  // ar[b][q][*] = sum_k S * V[k][*]; write packed bf16 pairs into dead Q region
  for (int i = t; i < 3072; i += 256) {
    int r = i >> 6, dp = i & 63;
    int b = r / 6;
    const float* sr = sb + b*36 + (r - b*6)*6;
    float a0 = 0.f, a1 = 0.f;
    #pragma unroll
    for (int k = 0; k < 6; k++) {
      uint32_t vu = *(const uint32_t*)(qs + (b*6 + k)*LQ + 256 + dp*2);
      a0 += sr[k] * u2f(vu << 16);
      a1 += sr[k] * u2f(vu & 0xFFFF0000u);
    }
    uint32_t pk = (uint32_t)f2bf(a0) | ((uint32_t)f2bf(a1) << 16);
    *((uint32_t*)(qs + r*LQ) + dp) = pk;
  }
  __syncthreads();

  // LN1 stats over m=[x(128), ar(128)]: 48 rows x 4 lanes
  if (t < 192) {
    int r = t >> 2, p = t & 3;
    const uint32_t* src = (p < 2) ? (const uint32_t*)(xs + r*LX + p*64)
                                  : (const uint32_t*)(qs + r*LQ + (p - 2)*64);
    float s1 = 0.f, s2 = 0.f;
    #pragma unroll 8
    for (int d = 0; d < 32; d++) {
      uint32_t u = src[d];
      float a = u2f(u << 16), b = u2f(u & 0xFFFF0000u);
      s1 += a + b; s2 += a*a + b*b;
    }
    s1 += __shfl_xor(s1, 1); s2 += __shfl_xor(s2, 1);
    s1 += __shfl_xor(s1, 2); s2 += __shfl_xor(s2, 2);
    float mu = s1 * (1.f/256.f);
    float var = s2 * (1.f/256.f) - mu*mu;
    if (p == 0) { smu[r] = mu; srs[r] = rsqrtf(var + 1e-5f); }
  }
  __syncthreads();

  // write Nmat (coalesced bf16x8)
  for (int i = t; i < 1536; i += 256) {
    int r = i >> 5, c0 = (i & 31) * 8;
    float mu = smu[r], rs = srs[r];
    const uint16_t* src = (c0 < 128) ? (xs + r*LX + c0) : (qs + r*LQ + (c0 - 128));
    bf16x8 v = *(const bf16x8*)src;
    bf16x8 o;
    #pragma unroll
    for (int j = 0; j < 8; j++)
      o[j] = (short)f2bf((bf2f((uint16_t)v[j]) - mu) * rs * g1[c0+j] + be1[c0+j]);
    *(bf16x8*)(Nmat + (r0+r)*256 + c0) = o;
  }
  // persist ar
  for (int i = t; i < 768; i += 256) {
    int r = i >> 4, c0 = (i & 15) * 8;
    *(bf16x8*)(AR + (r0+r)*128 + c0) = *(const bf16x8*)(qs + r*LQ + c0);
  }
}

// ---------------- K3: h = n @ W_fp + b_fp, then LN2 -> f bf16 ----------------
#define LH 264   // hs row stride (bf16 elems), 528B
__global__ __launch_bounds__(256) void fp_ln2(
    const uint16_t* __restrict__ Nmat, const uint16_t* __restrict__ WfpT,
    const float* __restrict__ b_fp, const float* __restrict__ X,
    const uint16_t* __restrict__ AR, const float* __restrict__ g2,
    const float* __restrict__ be2, uint16_t* __restrict__ F)
{
  __shared__ uint16_t As[64 * 32];      // 4 KB linear
  __shared__ uint16_t Bs[256 * 32];     // 16 KB linear
  __shared__ uint16_t hs[64 * LH];      // 33 KB padded
  __shared__ float smu[64], srs[64];
  int t = threadIdx.x;
  int lane = t & 63, wave = t >> 6;
  size_t m0 = (size_t)blockIdx.x * 64;

  int r_sub = (wave << 4) + (lane >> 2);
  int c_sub = (lane & 3) * 8;
  const uint16_t* Ag = Nmat + (m0 + r_sub) * 256 + c_sub;
  const uint16_t* Bg = WfpT + (size_t)r_sub * 256 + c_sub;
  uint16_t* lA = As + wave * 512;

  f32x4 acc[4][4] = {};
  for (int k0 = 0; k0 < 256; k0 += 32) {
    __syncthreads();
    gl2lds16(Ag + k0, lA);
    #pragma unroll
    for (int s = 0; s < 4; s++)
      gl2lds16(Bg + (size_t)s * 64 * 256 + k0, Bs + s * 2048 + wave * 512);
    __syncthreads();
    int lr = lane & 15, lh = lane >> 4;
    bf16x8 af[4], bfr[4];
    #pragma unroll
    for (int i = 0; i < 4; i++) {
      af[i]  = *(const bf16x8*)(As + (i*16 + lr) * 32 + lh*8);
      bfr[i] = *(const bf16x8*)(Bs + (wave*64 + i*16 + lr) * 32 + lh*8);
    }
    #pragma unroll
    for (int i = 0; i < 4; i++)
      #pragma unroll
      for (int j = 0; j < 4; j++)
        acc[i][j] = __builtin_amdgcn_mfma_f32_16x16x32_bf16(af[i], bfr[j], acc[i][j], 0, 0, 0);
  }
  { // h (+bias) -> LDS bf16
    int lr = lane & 15, lh = lane >> 4;
    #pragma unroll
    for (int i = 0; i < 4; i++)
      #pragma unroll
      for (int j = 0; j < 4; j++) {
        int col = wave*64 + j*16 + lr;
        float bv = b_fp[col];
        #pragma unroll
        for (int r = 0; r < 4; r++)
          hs[(i*16 + lh*4 + r) * LH + col] = f2bf(acc[i][j][r] + bv);
      }
  }
  __syncthreads();
  // LN2 stats: 64 rows x 4 lanes; row = [h(256) | x(128) | ar(128)]
  {
    int r = t >> 2, p = t & 3;
    size_t row = m0 + r;
    float s1 = 0.f, s2 = 0.f;
    if (p < 2) {
      const uint32_t* h = (const uint32_t*)(hs + r*LH + p*128);
      #pragma unroll 8
      for (int d = 0; d < 64; d++) {
        uint32_t u = h[d];
        float a = u2f(u << 16), b = u2f(u & 0xFFFF0000u);
        s1 += a + b; s2 += a*a + b*b;
      }
    } else if (p == 2) {
      const f32x4* xr = (const f32x4*)(X + row * 128);
      #pragma unroll 8
      for (int d = 0; d < 32; d++) {
        f32x4 v = xr[d];
        s1 += v[0]+v[1]+v[2]+v[3];
        s2 += v[0]*v[0]+v[1]*v[1]+v[2]*v[2]+v[3]*v[3];
      }
    } else {
      const uint32_t* ar = (const uint32_t*)(AR + row * 128);
      #pragma unroll 8
      for (int d = 0; d < 64; d++) {
        uint32_t u = ar[d];
        float a = u2f(u << 16), b = u2f(u & 0xFFFF0000u);
        s1 += a + b; s2 += a*a + b*b;
      }
    }
    s1 += __shfl_xor(s1, 1); s2 += __shfl_xor(s2, 1);
    s1 += __shfl_xor(s1, 2); s2 += __shfl_xor(s2, 2);
    float mu = s1 * (1.f/512.f);
    float var = s2 * (1.f/512.f) - mu*mu;
    if (p == 0) { smu[r] = mu; srs[r] = rsqrtf(var + 1e-5f); }
  }
  __syncthreads();
  // write F (coalesced bf16x8): row = [h(256) | x(128) | ar(128)]
  for (int i = t; i < 4096; i += 256) {
    int r = i >> 6, c0 = (i & 63) * 8;
    size_t row = m0 + r;
    float mu = smu[r], rs = srs[r];
    float src[8];
    if (c0 < 256) {
      bf16x8 v = *(const bf16x8*)(hs + r*LH + c0);
      #pragma unroll
      for (int j = 0; j < 8; j++) src[j] = bf2f((uint16_t)v[j]);
    } else if (c0 < 384) {
      const float* xr = X + row * 128 + (c0 - 256);
      f32x4 v0 = *(const f32x4*)xr, v1 = *(const f32x4*)(xr + 4);
      #pragma unroll
      for (int j = 0; j < 4; j++) { src[j] = v0[j]; src[4+j] = v1[j]; }
    } else {
      bf16x8 v = *(const bf16x8*)(AR + row * 128 + (c0 - 384));
      #pragma unroll
      for (int j = 0; j < 8; j++) src[j] = bf2f((uint16_t)v[j]);
    }
    bf16x8 o;
    #pragma unroll
    for (int j = 0; j < 8; j++)
      o[j] = (short)f2bf((src[j] - mu) * rs * g2[c0+j] + be2[c0+j]);
    *(bf16x8*)(F + row * 512 + c0) = o;
  }
}

// ---------------- K4: out = relu(f @ W_s + b_s) ----------------
// m97 structure: BK=64, linear LDS, gload_lds w16, XCD-chunked swizzle
__global__ __launch_bounds__(256) void out_gemm(
    const uint16_t* __restrict__ F, const uint16_t* __restrict__ WsT,
    const float* __restrict__ b_s, float* __restrict__ OUT)
{
  __shared__ uint16_t As[128 * 64];   // 16 KB linear
  __shared__ uint16_t Bs[128 * 64];   // 16 KB linear
  int t = threadIdx.x;
  int lane = t & 63, wave = t >> 6;
  int wm = wave >> 1, wn = wave & 1;

  int bid = blockIdx.x;
  int swz = (bid & 7) * 256 + (bid >> 3);
  size_t m0 = (size_t)(swz >> 3) * 128;
  int n0 = (swz & 7) * 128;

  int rl = lane >> 3;           // 0..7 rows within an issue
  int cl = (lane & 7) * 8;      // 8 bf16 cols
  const uint16_t* Ag = F   + (m0 + wave*32 + rl) * 3072 + cl;
  const uint16_t* Bg = WsT + (size_t)(n0 + wave*32 + rl) * 3072 + cl;
  uint16_t* lA = As + wave * 32 * 64;
  uint16_t* lB = Bs + wave * 32 * 64;

  f32x4 acc[4][4] = {};
  for (int k0 = 0; k0 < 3072; k0 += 64) {
    __syncthreads();
    #pragma unroll
    for (int s = 0; s < 4; s++) {
      gl2lds16(Ag + (size_t)(s*8) * 3072 + k0, lA + s*8*64);
      gl2lds16(Bg + (size_t)(s*8) * 3072 + k0, lB + s*8*64);
    }
    __syncthreads();
    int lr = lane & 15, lh = lane >> 4;
    #pragma unroll
    for (int ks = 0; ks < 2; ks++) {
      bf16x8 af[4], bfr[4];
      #pragma unroll
      for (int i = 0; i < 4; i++) {
        af[i]  = *(const bf16x8*)(As + (wm*64 + i*16 + lr) * 64 + ks*32 + lh*8);
        bfr[i] = *(const bf16x8*)(Bs + (wn*64 + i*16 + lr) * 64 + ks*32 + lh*8);
      }
      #pragma unroll
      for (int i = 0; i < 4; i++)
        #pragma unroll
        for (int j = 0; j < 4; j++)
          acc[i][j] = __builtin_amdgcn_mfma_f32_16x16x32_bf16(af[i], bfr[j], acc[i][j], 0, 0, 0);
    }
  }
  int lr = lane & 15, lh = lane >> 4;
  #pragma unroll
  for (int i = 0; i < 4; i++)
    #pragma unroll
    for (int j = 0; j < 4; j++) {
      int col = n0 + wn*64 + j*16 + lr;
      float bv = b_s[col];
      #pragma unroll
      for (int r = 0; r < 4; r++) {
        size_t row = m0 + wm*64 + i*16 + lh*4 + r;
        OUT[row * 1024 + col] = fmaxf(acc[i][j][r] + bv, 0.f);
      }
    }
}

extern "C" void kernel_launch(void* const* d_in, const int* in_sizes, int n_in,
                              void* d_out, int out_size, void* d_ws, size_t ws_size,
                              hipStream_t stream) {
  const float* x    = (const float*)d_in[0];
  const float* Wqkv = (const float*)d_in[1];
  const float* bqkv = (const float*)d_in[2];
  const float* g1   = (const float*)d_in[3];
  const float* be1  = (const float*)d_in[4];
  const float* Wfp  = (const float*)d_in[5];
  const float* bfp  = (const float*)d_in[6];
  const float* g2   = (const float*)d_in[7];
  const float* be2  = (const float*)d_in[8];
  const float* Ws   = (const float*)d_in[9];
  const float* bs   = (const float*)d_in[10];
  float* out = (float*)d_out;

  uint8_t* ws = (uint8_t*)d_ws;
  uint16_t* F     = (uint16_t*)(ws);                  // overlays QKV (dead by K3)
  uint16_t* QKV   = (uint16_t*)(ws);
  uint16_t* AR    = (uint16_t*)(ws + 201326592ull);
  uint16_t* Nmat  = (uint16_t*)(ws + 251658240ull);
  uint16_t* WqkvT = (uint16_t*)(ws + 352321536ull);
  uint16_t* WfpT  = (uint16_t*)(ws + 352419840ull);
  uint16_t* WsT   = (uint16_t*)(ws + 352550912ull);

  transpose_cvt<<<dim3(12, 4), 256, 0, stream>>>(Wqkv, WqkvT, 128, 384);
  transpose_cvt<<<dim3(8, 8), 256, 0, stream>>>(Wfp, WfpT, 256, 256);
  transpose_cvt<<<dim3(32, 96), 256, 0, stream>>>(Ws, WsT, 3072, 1024);
  qkv_gemm<<<dim3(1536, 3), 256, 0, stream>>>(x, WqkvT, bqkv, QKV);
  attn_ln1<<<dim3(4096), 256, 0, stream>>>(QKV, x, g1, be1, Nmat, AR);
  fp_ln2<<<dim3(3072), 256, 0, stream>>>(Nmat, WfpT, bfp, x, AR, g2, be2, F);
  out_gemm<<<dim3(2048), 256, 0, stream>>>(F, WsT, bs, out);
}

// Round 4
// 556.911 us; speedup vs baseline: 1.6676x; 1.3268x over previous
//
#include <hip/hip_runtime.h>
#include <stdint.h>

typedef short bf16x8 __attribute__((ext_vector_type(8)));
typedef float f32x4 __attribute__((ext_vector_type(4)));

__device__ __forceinline__ float bf2f(uint16_t b){
  union { uint32_t u; float f; } v; v.u = ((uint32_t)b) << 16; return v.f;
}
__device__ __forceinline__ float u2f(uint32_t u){
  union { uint32_t u; float f; } v; v.u = u; return v.f;
}
__device__ __forceinline__ uint16_t f2bf(float f){
  union { float f; uint32_t u; } v; v.f = f;
  uint32_t u = v.u;
  return (uint16_t)((u + 0x7FFFu + ((u >> 16) & 1u)) >> 16);
}

// async global->LDS, 16B per lane; lds base wave-uniform (HW adds lane*16)
__device__ __forceinline__ void gl2lds16(const uint16_t* g, uint16_t* l) {
  __builtin_amdgcn_global_load_lds((const __attribute__((address_space(1))) void*)g,
                                   (__attribute__((address_space(3))) void*)l, 16, 0, 0);
}

// ---------------- weight transpose + f32->bf16 convert ----------------
__global__ __launch_bounds__(256) void transpose_cvt(
    const float* __restrict__ src, uint16_t* __restrict__ dst, int K, int N)
{
  __shared__ float tile[32][33];
  int n0 = blockIdx.x * 32, k0 = blockIdx.y * 32;
  int tx = threadIdx.x & 31, ty = threadIdx.x >> 5;
  #pragma unroll
  for (int i = 0; i < 4; i++)
    tile[ty + 8*i][tx] = src[(size_t)(k0 + ty + 8*i) * N + n0 + tx];
  __syncthreads();
  #pragma unroll
  for (int i = 0; i < 4; i++)
    dst[(size_t)(n0 + ty + 8*i) * K + k0 + tx] = f2bf(tile[tx][ty + 8*i]);
}

// ---------------- fused mid: qkv GEMM + attn(6x6) + LN1 + fp GEMM + LN2 -> F ----
// 48 rows (8 b's) per block; all intermediates in LDS; weights read from L2 as
// MFMA B-fragments (WqkvT 96KB + WfpT 128KB, L2-hot).
#define LX 136   // xs row stride (bf16): 272B -> 4-bank shift per row
#define LQ 392   // qs row stride: 784B -> 4-bank shift
#define LNM 264  // nm row stride: 528B -> 4-bank shift

__global__ __launch_bounds__(256) void fused_mid(
    const float* __restrict__ X, const uint16_t* __restrict__ WqkvT,
    const float* __restrict__ bqkv, const float* __restrict__ g1,
    const float* __restrict__ be1, const uint16_t* __restrict__ WfpT,
    const float* __restrict__ bfp, const float* __restrict__ g2,
    const float* __restrict__ be2, uint16_t* __restrict__ F)
{
  __shared__ uint16_t xs[48 * LX];    // 12.8 KB  x as bf16
  __shared__ uint16_t qs[48 * LQ];    // 36.8 KB  [0:128)=Q->ar, [128:256)=K, [256:384)=V
  __shared__ uint16_t nm[48 * LNM];   // 24.8 KB  n, later h
  __shared__ float    sb[8 * 36];
  __shared__ float    smu[48], srs[48];
  int t = threadIdx.x;
  int lane = t & 63, wave = t >> 6;
  int lr = lane & 15, lh = lane >> 4;
  size_t r0 = (size_t)blockIdx.x * 48;

  // ---- stage x -> xs (bf16) ----
  for (int i = t; i < 768; i += 256) {
    int row = i >> 4, c = (i & 15) * 8;
    const float* g = X + (r0 + row) * 128 + c;
    f32x4 v0 = *(const f32x4*)g, v1 = *(const f32x4*)(g + 4);
    bf16x8 o;
    #pragma unroll
    for (int j = 0; j < 4; j++) { o[j] = (short)f2bf(v0[j]); o[4+j] = (short)f2bf(v1[j]); }
    *(bf16x8*)(xs + row * LX + c) = o;
  }
  __syncthreads();

  // ---- qkv GEMM: 48x384 = xs(48x128) @ WqkvT^T; wave covers 96 cols ----
  {
    f32x4 acc[3][6] = {};
    #pragma unroll
    for (int k0 = 0; k0 < 128; k0 += 32) {
      bf16x8 af[3], bw[6];
      #pragma unroll
      for (int i = 0; i < 3; i++)
        af[i] = *(const bf16x8*)(xs + (i*16 + lr) * LX + k0 + lh*8);
      #pragma unroll
      for (int j = 0; j < 6; j++)
        bw[j] = *(const bf16x8*)(WqkvT + (size_t)(wave*96 + j*16 + lr) * 128 + k0 + lh*8);
      #pragma unroll
      for (int i = 0; i < 3; i++)
        #pragma unroll
        for (int j = 0; j < 6; j++)
          acc[i][j] = __builtin_amdgcn_mfma_f32_16x16x32_bf16(af[i], bw[j], acc[i][j], 0, 0, 0);
    }
    #pragma unroll
    for (int i = 0; i < 3; i++)
      #pragma unroll
      for (int j = 0; j < 6; j++) {
        int col = wave*96 + j*16 + lr;
        float bv = bqkv[col];
        #pragma unroll
        for (int r = 0; r < 4; r++)
          qs[(i*16 + lh*4 + r) * LQ + col] = f2bf(acc[i][j][r] + bv);
      }
  }
  __syncthreads();

  // ---- S[b][q][k] = Q_row(q) . K_row(k) ----
  for (int i = t; i < 288; i += 256) {
    int b = i / 36, q = (i / 6) % 6, k = i % 6;
    const uint32_t* Qr = (const uint32_t*)(qs + (b*6 + q) * LQ);
    const uint32_t* Kr = (const uint32_t*)(qs + (b*6 + k) * LQ + 128);
    float s = 0.f;
    #pragma unroll 8
    for (int d = 0; d < 64; d++) {
      uint32_t qu = Qr[d], ku = Kr[d];
      s += u2f(qu << 16) * u2f(ku << 16) + u2f(qu & 0xFFFF0000u) * u2f(ku & 0xFFFF0000u);
    }
    sb[i] = s;
  }
  __syncthreads();

  // ---- ar = S @ V -> packed bf16 into dead Q region ----
  for (int i = t; i < 3072; i += 256) {
    int r = i >> 6, dp = i & 63;
    int b = r / 6;
    const float* sr = sb + b*36 + (r - b*6)*6;
    float a0 = 0.f, a1 = 0.f;
    #pragma unroll
    for (int k = 0; k < 6; k++) {
      uint32_t vu = *(const uint32_t*)(qs + (b*6 + k)*LQ + 256 + dp*2);
      a0 += sr[k] * u2f(vu << 16);
      a1 += sr[k] * u2f(vu & 0xFFFF0000u);
    }
    *((uint32_t*)(qs + r*LQ) + dp) = (uint32_t)f2bf(a0) | ((uint32_t)f2bf(a1) << 16);
  }
  __syncthreads();

  // ---- LN1 stats over [x(128), ar(128)] ----
  if (t < 192) {
    int r = t >> 2, p = t & 3;
    const uint32_t* src = (p < 2) ? (const uint32_t*)(xs + r*LX + p*64)
                                  : (const uint32_t*)(qs + r*LQ + (p - 2)*64);
    float s1 = 0.f, s2 = 0.f;
    #pragma unroll 8
    for (int d = 0; d < 32; d++) {
      uint32_t u = src[d];
      float a = u2f(u << 16), b = u2f(u & 0xFFFF0000u);
      s1 += a + b; s2 += a*a + b*b;
    }
    s1 += __shfl_xor(s1, 1); s2 += __shfl_xor(s2, 1);
    s1 += __shfl_xor(s1, 2); s2 += __shfl_xor(s2, 2);
    float mu = s1 * (1.f/256.f);
    float var = s2 * (1.f/256.f) - mu*mu;
    if (p == 0) { smu[r] = mu; srs[r] = rsqrtf(var + 1e-5f); }
  }
  __syncthreads();

  // ---- n = LN1(m) -> nm ----
  for (int i = t; i < 1536; i += 256) {
    int r = i >> 5, c0 = (i & 31) * 8;
    float mu = smu[r], rs = srs[r];
    const uint16_t* src = (c0 < 128) ? (xs + r*LX + c0) : (qs + r*LQ + (c0 - 128));
    bf16x8 v = *(const bf16x8*)src;
    bf16x8 o;
    #pragma unroll
    for (int j = 0; j < 8; j++)
      o[j] = (short)f2bf((bf2f((uint16_t)v[j]) - mu) * rs * g1[c0+j] + be1[c0+j]);
    *(bf16x8*)(nm + r*LNM + c0) = o;
  }
  __syncthreads();

  // ---- fp GEMM: h = n(48x256) @ WfpT^T; wave covers 64 cols ----
  f32x4 acc2[3][4] = {};
  #pragma unroll
  for (int k0 = 0; k0 < 256; k0 += 32) {
    bf16x8 af[3], bw[4];
    #pragma unroll
    for (int i = 0; i < 3; i++)
      af[i] = *(const bf16x8*)(nm + (i*16 + lr) * LNM + k0 + lh*8);
    #pragma unroll
    for (int j = 0; j < 4; j++)
      bw[j] = *(const bf16x8*)(WfpT + (size_t)(wave*64 + j*16 + lr) * 256 + k0 + lh*8);
    #pragma unroll
    for (int i = 0; i < 3; i++)
      #pragma unroll
      for (int j = 0; j < 4; j++)
        acc2[i][j] = __builtin_amdgcn_mfma_f32_16x16x32_bf16(af[i], bw[j], acc2[i][j], 0, 0, 0);
  }
  __syncthreads();   // all nm reads done before overwrite

  // ---- h + bias -> nm (overwrite) ----
  #pragma unroll
  for (int i = 0; i < 3; i++)
    #pragma unroll
    for (int j = 0; j < 4; j++) {
      int col = wave*64 + j*16 + lr;
      float bv = bfp[col];
      #pragma unroll
      for (int r = 0; r < 4; r++)
        nm[(i*16 + lh*4 + r) * LNM + col] = f2bf(acc2[i][j][r] + bv);
    }
  __syncthreads();

  // ---- LN2 stats over [h(256) | x(128) | ar(128)] ----
  if (t < 192) {
    int r = t >> 2, p = t & 3;
    const uint32_t* src = (p < 2) ? (const uint32_t*)(nm + r*LNM + p*128)
                        : (p == 2) ? (const uint32_t*)(xs + r*LX)
                                   : (const uint32_t*)(qs + r*LQ);
    float s1 = 0.f, s2 = 0.f;
    #pragma unroll 8
    for (int d = 0; d < 64; d++) {
      uint32_t u = src[d];
      float a = u2f(u << 16), b = u2f(u & 0xFFFF0000u);
      s1 += a + b; s2 += a*a + b*b;
    }
    s1 += __shfl_xor(s1, 1); s2 += __shfl_xor(s2, 1);
    s1 += __shfl_xor(s1, 2); s2 += __shfl_xor(s2, 2);
    float mu = s1 * (1.f/512.f);
    float var = s2 * (1.f/512.f) - mu*mu;
    if (p == 0) { smu[r] = mu; srs[r] = rsqrtf(var + 1e-5f); }
  }
  __syncthreads();

  // ---- f = LN2([h|x|ar]) -> F (coalesced bf16x8) ----
  for (int i = t; i < 3072; i += 256) {
    int r = i >> 6, c0 = (i & 63) * 8;
    float mu = smu[r], rs = srs[r];
    const uint16_t* src = (c0 < 256) ? (nm + r*LNM + c0)
                        : (c0 < 384) ? (xs + r*LX + (c0 - 256))
                                     : (qs + r*LQ + (c0 - 384));
    bf16x8 v = *(const bf16x8*)src;
    bf16x8 o;
    #pragma unroll
    for (int j = 0; j < 8; j++)
      o[j] = (short)f2bf((bf2f((uint16_t)v[j]) - mu) * rs * g2[c0+j] + be2[c0+j]);
    *(bf16x8*)(F + (r0 + r) * 512 + c0) = o;
  }
}

// ---------------- K4: out = relu(f @ W_s + b_s) ----------------
// m97 structure: BK=64, linear LDS, gload_lds w16, XCD-chunked swizzle
__global__ __launch_bounds__(256) void out_gemm(
    const uint16_t* __restrict__ F, const uint16_t* __restrict__ WsT,
    const float* __restrict__ b_s, float* __restrict__ OUT)
{
  __shared__ uint16_t As[128 * 64];   // 16 KB linear
  __shared__ uint16_t Bs[128 * 64];   // 16 KB linear
  int t = threadIdx.x;
  int lane = t & 63, wave = t >> 6;
  int wm = wave >> 1, wn = wave & 1;

  int bid = blockIdx.x;
  int swz = (bid & 7) * 256 + (bid >> 3);
  size_t m0 = (size_t)(swz >> 3) * 128;
  int n0 = (swz & 7) * 128;

  int rl = lane >> 3;           // 0..7 rows within an issue
  int cl = (lane & 7) * 8;      // 8 bf16 cols
  const uint16_t* Ag = F   + (m0 + wave*32 + rl) * 3072 + cl;
  const uint16_t* Bg = WsT + (size_t)(n0 + wave*32 + rl) * 3072 + cl;
  uint16_t* lA = As + wave * 32 * 64;
  uint16_t* lB = Bs + wave * 32 * 64;

  f32x4 acc[4][4] = {};
  for (int k0 = 0; k0 < 3072; k0 += 64) {
    __syncthreads();
    #pragma unroll
    for (int s = 0; s < 4; s++) {
      gl2lds16(Ag + (size_t)(s*8) * 3072 + k0, lA + s*8*64);
      gl2lds16(Bg + (size_t)(s*8) * 3072 + k0, lB + s*8*64);
    }
    __syncthreads();
    int lr = lane & 15, lh = lane >> 4;
    #pragma unroll
    for (int ks = 0; ks < 2; ks++) {
      bf16x8 af[4], bfr[4];
      #pragma unroll
      for (int i = 0; i < 4; i++) {
        af[i]  = *(const bf16x8*)(As + (wm*64 + i*16 + lr) * 64 + ks*32 + lh*8);
        bfr[i] = *(const bf16x8*)(Bs + (wn*64 + i*16 + lr) * 64 + ks*32 + lh*8);
      }
      #pragma unroll
      for (int i = 0; i < 4; i++)
        #pragma unroll
        for (int j = 0; j < 4; j++)
          acc[i][j] = __builtin_amdgcn_mfma_f32_16x16x32_bf16(af[i], bfr[j], acc[i][j], 0, 0, 0);
    }
  }
  int lr = lane & 15, lh = lane >> 4;
  #pragma unroll
  for (int i = 0; i < 4; i++)
    #pragma unroll
    for (int j = 0; j < 4; j++) {
      int col = n0 + wn*64 + j*16 + lr;
      float bv = b_s[col];
      #pragma unroll
      for (int r = 0; r < 4; r++) {
        size_t row = m0 + wm*64 + i*16 + lh*4 + r;
        OUT[row * 1024 + col] = fmaxf(acc[i][j][r] + bv, 0.f);
      }
    }
}

extern "C" void kernel_launch(void* const* d_in, const int* in_sizes, int n_in,
                              void* d_out, int out_size, void* d_ws, size_t ws_size,
                              hipStream_t stream) {
  const float* x    = (const float*)d_in[0];
  const float* Wqkv = (const float*)d_in[1];
  const float* bqkv = (const float*)d_in[2];
  const float* g1   = (const float*)d_in[3];
  const float* be1  = (const float*)d_in[4];
  const float* Wfp  = (const float*)d_in[5];
  const float* bfp  = (const float*)d_in[6];
  const float* g2   = (const float*)d_in[7];
  const float* be2  = (const float*)d_in[8];
  const float* Ws   = (const float*)d_in[9];
  const float* bs   = (const float*)d_in[10];
  float* out = (float*)d_out;

  uint8_t* ws = (uint8_t*)d_ws;
  uint16_t* F     = (uint16_t*)(ws);                  // 32768x3072 bf16, 201.3 MB
  uint16_t* WqkvT = (uint16_t*)(ws + 201326592ull);   // 384x128 bf16
  uint16_t* WfpT  = (uint16_t*)(ws + 201424896ull);   // 256x256 bf16
  uint16_t* WsT   = (uint16_t*)(ws + 201555968ull);   // 1024x3072 bf16

  transpose_cvt<<<dim3(12, 4), 256, 0, stream>>>(Wqkv, WqkvT, 128, 384);
  transpose_cvt<<<dim3(8, 8), 256, 0, stream>>>(Wfp, WfpT, 256, 256);
  transpose_cvt<<<dim3(32, 96), 256, 0, stream>>>(Ws, WsT, 3072, 1024);
  fused_mid<<<dim3(4096), 256, 0, stream>>>(x, WqkvT, bqkv, g1, be1,
                                            WfpT, bfp, g2, be2, F);
  out_gemm<<<dim3(2048), 256, 0, stream>>>(F, WsT, bs, out);
}

// Round 5
// 499.396 us; speedup vs baseline: 1.8597x; 1.1152x over previous
//
#include <hip/hip_runtime.h>
#include <stdint.h>

typedef short bf16x8 __attribute__((ext_vector_type(8)));
typedef float f32x4 __attribute__((ext_vector_type(4)));

__device__ __forceinline__ float bf2f(uint16_t b){
  union { uint32_t u; float f; } v; v.u = ((uint32_t)b) << 16; return v.f;
}
__device__ __forceinline__ float u2f(uint32_t u){
  union { uint32_t u; float f; } v; v.u = u; return v.f;
}
__device__ __forceinline__ uint16_t f2bf(float f){
  union { float f; uint32_t u; } v; v.f = f;
  uint32_t u = v.u;
  return (uint16_t)((u + 0x7FFFu + ((u >> 16) & 1u)) >> 16);
}

// async global->LDS, 16B per lane; lds base wave-uniform (HW adds lane*16)
__device__ __forceinline__ void gl2lds16(const uint16_t* g, uint16_t* l) {
  __builtin_amdgcn_global_load_lds((const __attribute__((address_space(1))) void*)g,
                                   (__attribute__((address_space(3))) void*)l, 16, 0, 0);
}

// ---------------- weight transpose + f32->bf16 convert ----------------
__global__ __launch_bounds__(256) void transpose_cvt(
    const float* __restrict__ src, uint16_t* __restrict__ dst, int K, int N)
{
  __shared__ float tile[32][33];
  int n0 = blockIdx.x * 32, k0 = blockIdx.y * 32;
  int tx = threadIdx.x & 31, ty = threadIdx.x >> 5;
  #pragma unroll
  for (int i = 0; i < 4; i++)
    tile[ty + 8*i][tx] = src[(size_t)(k0 + ty + 8*i) * N + n0 + tx];
  __syncthreads();
  #pragma unroll
  for (int i = 0; i < 4; i++)
    dst[(size_t)(n0 + ty + 8*i) * K + k0 + tx] = f2bf(tile[tx][ty + 8*i]);
}

// ---------------- fused mid: qkv GEMM + attn(6x6) + LN1 + fp GEMM + LN2 -> F ----
#define LX 136
#define LQ 392
#define LNM 264

__global__ __launch_bounds__(256) void fused_mid(
    const float* __restrict__ X, const uint16_t* __restrict__ WqkvT,
    const float* __restrict__ bqkv, const float* __restrict__ g1,
    const float* __restrict__ be1, const uint16_t* __restrict__ WfpT,
    const float* __restrict__ bfp, const float* __restrict__ g2,
    const float* __restrict__ be2, uint16_t* __restrict__ F)
{
  __shared__ uint16_t xs[48 * LX];
  __shared__ uint16_t qs[48 * LQ];
  __shared__ uint16_t nm[48 * LNM];
  __shared__ float    sb[8 * 36];
  __shared__ float    smu[48], srs[48];
  int t = threadIdx.x;
  int lane = t & 63, wave = t >> 6;
  int lr = lane & 15, lh = lane >> 4;
  size_t r0 = (size_t)blockIdx.x * 48;

  for (int i = t; i < 768; i += 256) {
    int row = i >> 4, c = (i & 15) * 8;
    const float* g = X + (r0 + row) * 128 + c;
    f32x4 v0 = *(const f32x4*)g, v1 = *(const f32x4*)(g + 4);
    bf16x8 o;
    #pragma unroll
    for (int j = 0; j < 4; j++) { o[j] = (short)f2bf(v0[j]); o[4+j] = (short)f2bf(v1[j]); }
    *(bf16x8*)(xs + row * LX + c) = o;
  }
  __syncthreads();

  {
    f32x4 acc[3][6] = {};
    #pragma unroll
    for (int k0 = 0; k0 < 128; k0 += 32) {
      bf16x8 af[3], bw[6];
      #pragma unroll
      for (int i = 0; i < 3; i++)
        af[i] = *(const bf16x8*)(xs + (i*16 + lr) * LX + k0 + lh*8);
      #pragma unroll
      for (int j = 0; j < 6; j++)
        bw[j] = *(const bf16x8*)(WqkvT + (size_t)(wave*96 + j*16 + lr) * 128 + k0 + lh*8);
      #pragma unroll
      for (int i = 0; i < 3; i++)
        #pragma unroll
        for (int j = 0; j < 6; j++)
          acc[i][j] = __builtin_amdgcn_mfma_f32_16x16x32_bf16(af[i], bw[j], acc[i][j], 0, 0, 0);
    }
    #pragma unroll
    for (int i = 0; i < 3; i++)
      #pragma unroll
      for (int j = 0; j < 6; j++) {
        int col = wave*96 + j*16 + lr;
        float bv = bqkv[col];
        #pragma unroll
        for (int r = 0; r < 4; r++)
          qs[(i*16 + lh*4 + r) * LQ + col] = f2bf(acc[i][j][r] + bv);
      }
  }
  __syncthreads();

  for (int i = t; i < 288; i += 256) {
    int b = i / 36, q = (i / 6) % 6, k = i % 6;
    const uint32_t* Qr = (const uint32_t*)(qs + (b*6 + q) * LQ);
    const uint32_t* Kr = (const uint32_t*)(qs + (b*6 + k) * LQ + 128);
    float s = 0.f;
    #pragma unroll 8
    for (int d = 0; d < 64; d++) {
      uint32_t qu = Qr[d], ku = Kr[d];
      s += u2f(qu << 16) * u2f(ku << 16) + u2f(qu & 0xFFFF0000u) * u2f(ku & 0xFFFF0000u);
    }
    sb[i] = s;
  }
  __syncthreads();

  for (int i = t; i < 3072; i += 256) {
    int r = i >> 6, dp = i & 63;
    int b = r / 6;
    const float* sr = sb + b*36 + (r - b*6)*6;
    float a0 = 0.f, a1 = 0.f;
    #pragma unroll
    for (int k = 0; k < 6; k++) {
      uint32_t vu = *(const uint32_t*)(qs + (b*6 + k)*LQ + 256 + dp*2);
      a0 += sr[k] * u2f(vu << 16);
      a1 += sr[k] * u2f(vu & 0xFFFF0000u);
    }
    *((uint32_t*)(qs + r*LQ) + dp) = (uint32_t)f2bf(a0) | ((uint32_t)f2bf(a1) << 16);
  }
  __syncthreads();

  if (t < 192) {
    int r = t >> 2, p = t & 3;
    const uint32_t* src = (p < 2) ? (const uint32_t*)(xs + r*LX + p*64)
                                  : (const uint32_t*)(qs + r*LQ + (p - 2)*64);
    float s1 = 0.f, s2 = 0.f;
    #pragma unroll 8
    for (int d = 0; d < 32; d++) {
      uint32_t u = src[d];
      float a = u2f(u << 16), b = u2f(u & 0xFFFF0000u);
      s1 += a + b; s2 += a*a + b*b;
    }
    s1 += __shfl_xor(s1, 1); s2 += __shfl_xor(s2, 1);
    s1 += __shfl_xor(s1, 2); s2 += __shfl_xor(s2, 2);
    float mu = s1 * (1.f/256.f);
    float var = s2 * (1.f/256.f) - mu*mu;
    if (p == 0) { smu[r] = mu; srs[r] = rsqrtf(var + 1e-5f); }
  }
  __syncthreads();

  for (int i = t; i < 1536; i += 256) {
    int r = i >> 5, c0 = (i & 31) * 8;
    float mu = smu[r], rs = srs[r];
    const uint16_t* src = (c0 < 128) ? (xs + r*LX + c0) : (qs + r*LQ + (c0 - 128));
    bf16x8 v = *(const bf16x8*)src;
    bf16x8 o;
    #pragma unroll
    for (int j = 0; j < 8; j++)
      o[j] = (short)f2bf((bf2f((uint16_t)v[j]) - mu) * rs * g1[c0+j] + be1[c0+j]);
    *(bf16x8*)(nm + r*LNM + c0) = o;
  }
  __syncthreads();

  f32x4 acc2[3][4] = {};
  #pragma unroll
  for (int k0 = 0; k0 < 256; k0 += 32) {
    bf16x8 af[3], bw[4];
    #pragma unroll
    for (int i = 0; i < 3; i++)
      af[i] = *(const bf16x8*)(nm + (i*16 + lr) * LNM + k0 + lh*8);
    #pragma unroll
    for (int j = 0; j < 4; j++)
      bw[j] = *(const bf16x8*)(WfpT + (size_t)(wave*64 + j*16 + lr) * 256 + k0 + lh*8);
    #pragma unroll
    for (int i = 0; i < 3; i++)
      #pragma unroll
      for (int j = 0; j < 4; j++)
        acc2[i][j] = __builtin_amdgcn_mfma_f32_16x16x32_bf16(af[i], bw[j], acc2[i][j], 0, 0, 0);
  }
  __syncthreads();

  #pragma unroll
  for (int i = 0; i < 3; i++)
    #pragma unroll
    for (int j = 0; j < 4; j++) {
      int col = wave*64 + j*16 + lr;
      float bv = bfp[col];
      #pragma unroll
      for (int r = 0; r < 4; r++)
        nm[(i*16 + lh*4 + r) * LNM + col] = f2bf(acc2[i][j][r] + bv);
    }
  __syncthreads();

  if (t < 192) {
    int r = t >> 2, p = t & 3;
    const uint32_t* src = (p < 2) ? (const uint32_t*)(nm + r*LNM + p*128)
                        : (p == 2) ? (const uint32_t*)(xs + r*LX)
                                   : (const uint32_t*)(qs + r*LQ);
    float s1 = 0.f, s2 = 0.f;
    #pragma unroll 8
    for (int d = 0; d < 64; d++) {
      uint32_t u = src[d];
      float a = u2f(u << 16), b = u2f(u & 0xFFFF0000u);
      s1 += a + b; s2 += a*a + b*b;
    }
    s1 += __shfl_xor(s1, 1); s2 += __shfl_xor(s2, 1);
    s1 += __shfl_xor(s1, 2); s2 += __shfl_xor(s2, 2);
    float mu = s1 * (1.f/512.f);
    float var = s2 * (1.f/512.f) - mu*mu;
    if (p == 0) { smu[r] = mu; srs[r] = rsqrtf(var + 1e-5f); }
  }
  __syncthreads();

  for (int i = t; i < 3072; i += 256) {
    int r = i >> 6, c0 = (i & 63) * 8;
    float mu = smu[r], rs = srs[r];
    const uint16_t* src = (c0 < 256) ? (nm + r*LNM + c0)
                        : (c0 < 384) ? (xs + r*LX + (c0 - 256))
                                     : (qs + r*LQ + (c0 - 384));
    bf16x8 v = *(const bf16x8*)src;
    bf16x8 o;
    #pragma unroll
    for (int j = 0; j < 8; j++)
      o[j] = (short)f2bf((bf2f((uint16_t)v[j]) - mu) * rs * g2[c0+j] + be2[c0+j]);
    *(bf16x8*)(F + (r0 + r) * 512 + c0) = o;
  }
}

// ---------------- K4: out = relu(f @ W_s + b_s) ----------------
// 128x128 tile, BK=32, 4-slot LDS ring, stage-2-ahead counted vmcnt,
// 1 raw barrier/K-tile, T2 both-sides swizzle, T5 setprio.
__global__ __launch_bounds__(256) void out_gemm(
    const uint16_t* __restrict__ F, const uint16_t* __restrict__ WsT,
    const float* __restrict__ b_s, float* __restrict__ OUT)
{
  __shared__ uint16_t lds[4][2][128*32];   // 64 KB: [slot][A/B][row*32+chunk*8]
  int t = threadIdx.x;
  int lane = t & 63, wave = t >> 6;
  int wm = wave >> 1, wn = wave & 1;
  int lr = lane & 15, lh = lane >> 4;

  int bid = blockIdx.x;
  int swz = (bid & 7) * 256 + (bid >> 3);
  size_t m0 = (size_t)(swz >> 3) * 128;
  int n0 = (swz & 7) * 128;

  // staging: all-thread issue covers 64 rows; LDS dest linear (tid*8 elems),
  // global source column pre-swizzled so LDS holds chunk^=( (row>>1)&3 )
  int srow = t >> 2;                            // 0..63
  int gch  = (t & 3) ^ ((t >> 3) & 3);          // inverse-swizzled source chunk
  const uint16_t* Ag = F   + (m0 + srow) * 3072 + gch * 8;
  const uint16_t* Bg = WsT + (size_t)(n0 + srow) * 3072 + gch * 8;

#define STAGE(s, tt) do {                                                   \
    int kk0 = (tt) * 32;                                                    \
    gl2lds16(Ag + kk0,                   &lds[s][0][0] + wave*512);         \
    gl2lds16(Ag + (size_t)64*3072 + kk0, &lds[s][0][0] + 2048 + wave*512);  \
    gl2lds16(Bg + kk0,                   &lds[s][1][0] + wave*512);         \
    gl2lds16(Bg + (size_t)64*3072 + kk0, &lds[s][1][0] + 2048 + wave*512);  \
  } while(0)

  f32x4 acc[4][4] = {};
  int swch = (lh ^ ((lr >> 1) & 3)) * 8;        // swizzled read chunk (elems)

#define COMPUTE(s) do {                                                     \
    const uint16_t* As_ = &lds[s][0][0];                                    \
    const uint16_t* Bs_ = &lds[s][1][0];                                    \
    bf16x8 af[4], bfr[4];                                                   \
    _Pragma("unroll")                                                       \
    for (int i = 0; i < 4; i++) {                                           \
      af[i]  = *(const bf16x8*)(As_ + (wm*64 + i*16 + lr)*32 + swch);       \
      bfr[i] = *(const bf16x8*)(Bs_ + (wn*64 + i*16 + lr)*32 + swch);       \
    }                                                                       \
    __builtin_amdgcn_s_setprio(1);                                          \
    _Pragma("unroll")                                                       \
    for (int i = 0; i < 4; i++)                                             \
      _Pragma("unroll")                                                     \
      for (int j = 0; j < 4; j++)                                           \
        acc[i][j] = __builtin_amdgcn_mfma_f32_16x16x32_bf16(af[i], bfr[j],  \
                                                            acc[i][j],0,0,0);\
    __builtin_amdgcn_s_setprio(0);                                          \
  } while(0)

  STAGE(0, 0);
  STAGE(1, 1);
  for (int tt = 0; tt < 94; ++tt) {
    STAGE((tt + 2) & 3, tt + 2);
    asm volatile("s_waitcnt vmcnt(8)" ::: "memory");   // tile tt landed; t+1,t+2 in flight
    __builtin_amdgcn_s_barrier();
    asm volatile("" ::: "memory");
    COMPUTE(tt & 3);
  }
  asm volatile("s_waitcnt vmcnt(4)" ::: "memory");     // tile 94 landed
  __builtin_amdgcn_s_barrier();
  asm volatile("" ::: "memory");
  COMPUTE(94 & 3);
  asm volatile("s_waitcnt vmcnt(0)" ::: "memory");     // tile 95 landed
  __builtin_amdgcn_s_barrier();
  asm volatile("" ::: "memory");
  COMPUTE(95 & 3);

#undef STAGE
#undef COMPUTE

  #pragma unroll
  for (int i = 0; i < 4; i++)
    #pragma unroll
    for (int j = 0; j < 4; j++) {
      int col = n0 + wn*64 + j*16 + lr;
      float bv = b_s[col];
      #pragma unroll
      for (int r = 0; r < 4; r++) {
        size_t row = m0 + wm*64 + i*16 + lh*4 + r;
        OUT[row * 1024 + col] = fmaxf(acc[i][j][r] + bv, 0.f);
      }
    }
}

extern "C" void kernel_launch(void* const* d_in, const int* in_sizes, int n_in,
                              void* d_out, int out_size, void* d_ws, size_t ws_size,
                              hipStream_t stream) {
  const float* x    = (const float*)d_in[0];
  const float* Wqkv = (const float*)d_in[1];
  const float* bqkv = (const float*)d_in[2];
  const float* g1   = (const float*)d_in[3];
  const float* be1  = (const float*)d_in[4];
  const float* Wfp  = (const float*)d_in[5];
  const float* bfp  = (const float*)d_in[6];
  const float* g2   = (const float*)d_in[7];
  const float* be2  = (const float*)d_in[8];
  const float* Ws   = (const float*)d_in[9];
  const float* bs   = (const float*)d_in[10];
  float* out = (float*)d_out;

  uint8_t* ws = (uint8_t*)d_ws;
  uint16_t* F     = (uint16_t*)(ws);                  // 32768x3072 bf16
  uint16_t* WqkvT = (uint16_t*)(ws + 201326592ull);
  uint16_t* WfpT  = (uint16_t*)(ws + 201424896ull);
  uint16_t* WsT   = (uint16_t*)(ws + 201555968ull);

  transpose_cvt<<<dim3(12, 4), 256, 0, stream>>>(Wqkv, WqkvT, 128, 384);
  transpose_cvt<<<dim3(8, 8), 256, 0, stream>>>(Wfp, WfpT, 256, 256);
  transpose_cvt<<<dim3(32, 96), 256, 0, stream>>>(Ws, WsT, 3072, 1024);
  fused_mid<<<dim3(4096), 256, 0, stream>>>(x, WqkvT, bqkv, g1, be1,
                                            WfpT, bfp, g2, be2, F);
  out_gemm<<<dim3(2048), 256, 0, stream>>>(F, WsT, bs, out);
}

// Round 6
// 426.645 us; speedup vs baseline: 2.1768x; 1.1705x over previous
//
#include <hip/hip_runtime.h>
#include <stdint.h>

typedef short bf16x8 __attribute__((ext_vector_type(8)));
typedef float f32x4 __attribute__((ext_vector_type(4)));

__device__ __forceinline__ float bf2f(uint16_t b){
  union { uint32_t u; float f; } v; v.u = ((uint32_t)b) << 16; return v.f;
}
__device__ __forceinline__ float u2f(uint32_t u){
  union { uint32_t u; float f; } v; v.u = u; return v.f;
}
__device__ __forceinline__ uint16_t f2bf(float f){
  union { float f; uint32_t u; } v; v.f = f;
  uint32_t u = v.u;
  return (uint16_t)((u + 0x7FFFu + ((u >> 16) & 1u)) >> 16);
}

// async global->LDS, 16B per lane; lds base wave-uniform (HW adds lane*16)
__device__ __forceinline__ void gl2lds16(const uint16_t* g, uint16_t* l) {
  __builtin_amdgcn_global_load_lds((const __attribute__((address_space(1))) void*)g,
                                   (__attribute__((address_space(3))) void*)l, 16, 0, 0);
}

// ---------------- weight transpose + f32->bf16 convert ----------------
__global__ __launch_bounds__(256) void transpose_cvt(
    const float* __restrict__ src, uint16_t* __restrict__ dst, int K, int N)
{
  __shared__ float tile[32][33];
  int n0 = blockIdx.x * 32, k0 = blockIdx.y * 32;
  int tx = threadIdx.x & 31, ty = threadIdx.x >> 5;
  #pragma unroll
  for (int i = 0; i < 4; i++)
    tile[ty + 8*i][tx] = src[(size_t)(k0 + ty + 8*i) * N + n0 + tx];
  __syncthreads();
  #pragma unroll
  for (int i = 0; i < 4; i++)
    dst[(size_t)(n0 + ty + 8*i) * K + k0 + tx] = f2bf(tile[tx][ty + 8*i]);
}

// ---------------- fused mid: qkv GEMM + attn(6x6) + LN1 + fp GEMM + LN2 -> F ----
#define LX 136
#define LQ 392
#define LNM 264

__global__ __launch_bounds__(256) void fused_mid(
    const float* __restrict__ X, const uint16_t* __restrict__ WqkvT,
    const float* __restrict__ bqkv, const float* __restrict__ g1,
    const float* __restrict__ be1, const uint16_t* __restrict__ WfpT,
    const float* __restrict__ bfp, const float* __restrict__ g2,
    const float* __restrict__ be2, uint16_t* __restrict__ F)
{
  __shared__ uint16_t xs[48 * LX];
  __shared__ uint16_t qs[48 * LQ];
  __shared__ uint16_t nm[48 * LNM];
  __shared__ float    sb[8 * 36];
  __shared__ float    smu[48], srs[48];
  int t = threadIdx.x;
  int lane = t & 63, wave = t >> 6;
  int lr = lane & 15, lh = lane >> 4;
  size_t r0 = (size_t)blockIdx.x * 48;

  for (int i = t; i < 768; i += 256) {
    int row = i >> 4, c = (i & 15) * 8;
    const float* g = X + (r0 + row) * 128 + c;
    f32x4 v0 = *(const f32x4*)g, v1 = *(const f32x4*)(g + 4);
    bf16x8 o;
    #pragma unroll
    for (int j = 0; j < 4; j++) { o[j] = (short)f2bf(v0[j]); o[4+j] = (short)f2bf(v1[j]); }
    *(bf16x8*)(xs + row * LX + c) = o;
  }
  __syncthreads();

  {
    f32x4 acc[3][6] = {};
    #pragma unroll
    for (int k0 = 0; k0 < 128; k0 += 32) {
      bf16x8 af[3], bw[6];
      #pragma unroll
      for (int i = 0; i < 3; i++)
        af[i] = *(const bf16x8*)(xs + (i*16 + lr) * LX + k0 + lh*8);
      #pragma unroll
      for (int j = 0; j < 6; j++)
        bw[j] = *(const bf16x8*)(WqkvT + (size_t)(wave*96 + j*16 + lr) * 128 + k0 + lh*8);
      #pragma unroll
      for (int i = 0; i < 3; i++)
        #pragma unroll
        for (int j = 0; j < 6; j++)
          acc[i][j] = __builtin_amdgcn_mfma_f32_16x16x32_bf16(af[i], bw[j], acc[i][j], 0, 0, 0);
    }
    #pragma unroll
    for (int i = 0; i < 3; i++)
      #pragma unroll
      for (int j = 0; j < 6; j++) {
        int col = wave*96 + j*16 + lr;
        float bv = bqkv[col];
        #pragma unroll
        for (int r = 0; r < 4; r++)
          qs[(i*16 + lh*4 + r) * LQ + col] = f2bf(acc[i][j][r] + bv);
      }
  }
  __syncthreads();

  for (int i = t; i < 288; i += 256) {
    int b = i / 36, q = (i / 6) % 6, k = i % 6;
    const uint32_t* Qr = (const uint32_t*)(qs + (b*6 + q) * LQ);
    const uint32_t* Kr = (const uint32_t*)(qs + (b*6 + k) * LQ + 128);
    float s = 0.f;
    #pragma unroll 8
    for (int d = 0; d < 64; d++) {
      uint32_t qu = Qr[d], ku = Kr[d];
      s += u2f(qu << 16) * u2f(ku << 16) + u2f(qu & 0xFFFF0000u) * u2f(ku & 0xFFFF0000u);
    }
    sb[i] = s;
  }
  __syncthreads();

  for (int i = t; i < 3072; i += 256) {
    int r = i >> 6, dp = i & 63;
    int b = r / 6;
    const float* sr = sb + b*36 + (r - b*6)*6;
    float a0 = 0.f, a1 = 0.f;
    #pragma unroll
    for (int k = 0; k < 6; k++) {
      uint32_t vu = *(const uint32_t*)(qs + (b*6 + k)*LQ + 256 + dp*2);
      a0 += sr[k] * u2f(vu << 16);
      a1 += sr[k] * u2f(vu & 0xFFFF0000u);
    }
    *((uint32_t*)(qs + r*LQ) + dp) = (uint32_t)f2bf(a0) | ((uint32_t)f2bf(a1) << 16);
  }
  __syncthreads();

  if (t < 192) {
    int r = t >> 2, p = t & 3;
    const uint32_t* src = (p < 2) ? (const uint32_t*)(xs + r*LX + p*64)
                                  : (const uint32_t*)(qs + r*LQ + (p - 2)*64);
    float s1 = 0.f, s2 = 0.f;
    #pragma unroll 8
    for (int d = 0; d < 32; d++) {
      uint32_t u = src[d];
      float a = u2f(u << 16), b = u2f(u & 0xFFFF0000u);
      s1 += a + b; s2 += a*a + b*b;
    }
    s1 += __shfl_xor(s1, 1); s2 += __shfl_xor(s2, 1);
    s1 += __shfl_xor(s1, 2); s2 += __shfl_xor(s2, 2);
    float mu = s1 * (1.f/256.f);
    float var = s2 * (1.f/256.f) - mu*mu;
    if (p == 0) { smu[r] = mu; srs[r] = rsqrtf(var + 1e-5f); }
  }
  __syncthreads();

  for (int i = t; i < 1536; i += 256) {
    int r = i >> 5, c0 = (i & 31) * 8;
    float mu = smu[r], rs = srs[r];
    const uint16_t* src = (c0 < 128) ? (xs + r*LX + c0) : (qs + r*LQ + (c0 - 128));
    bf16x8 v = *(const bf16x8*)src;
    bf16x8 o;
    #pragma unroll
    for (int j = 0; j < 8; j++)
      o[j] = (short)f2bf((bf2f((uint16_t)v[j]) - mu) * rs * g1[c0+j] + be1[c0+j]);
    *(bf16x8*)(nm + r*LNM + c0) = o;
  }
  __syncthreads();

  f32x4 acc2[3][4] = {};
  #pragma unroll
  for (int k0 = 0; k0 < 256; k0 += 32) {
    bf16x8 af[3], bw[4];
    #pragma unroll
    for (int i = 0; i < 3; i++)
      af[i] = *(const bf16x8*)(nm + (i*16 + lr) * LNM + k0 + lh*8);
    #pragma unroll
    for (int j = 0; j < 4; j++)
      bw[j] = *(const bf16x8*)(WfpT + (size_t)(wave*64 + j*16 + lr) * 256 + k0 + lh*8);
    #pragma unroll
    for (int i = 0; i < 3; i++)
      #pragma unroll
      for (int j = 0; j < 4; j++)
        acc2[i][j] = __builtin_amdgcn_mfma_f32_16x16x32_bf16(af[i], bw[j], acc2[i][j], 0, 0, 0);
  }
  __syncthreads();

  #pragma unroll
  for (int i = 0; i < 3; i++)
    #pragma unroll
    for (int j = 0; j < 4; j++) {
      int col = wave*64 + j*16 + lr;
      float bv = bfp[col];
      #pragma unroll
      for (int r = 0; r < 4; r++)
        nm[(i*16 + lh*4 + r) * LNM + col] = f2bf(acc2[i][j][r] + bv);
    }
  __syncthreads();

  if (t < 192) {
    int r = t >> 2, p = t & 3;
    const uint32_t* src = (p < 2) ? (const uint32_t*)(nm + r*LNM + p*128)
                        : (p == 2) ? (const uint32_t*)(xs + r*LX)
                                   : (const uint32_t*)(qs + r*LQ);
    float s1 = 0.f, s2 = 0.f;
    #pragma unroll 8
    for (int d = 0; d < 64; d++) {
      uint32_t u = src[d];
      float a = u2f(u << 16), b = u2f(u & 0xFFFF0000u);
      s1 += a + b; s2 += a*a + b*b;
    }
    s1 += __shfl_xor(s1, 1); s2 += __shfl_xor(s2, 1);
    s1 += __shfl_xor(s1, 2); s2 += __shfl_xor(s2, 2);
    float mu = s1 * (1.f/512.f);
    float var = s2 * (1.f/512.f) - mu*mu;
    if (p == 0) { smu[r] = mu; srs[r] = rsqrtf(var + 1e-5f); }
  }
  __syncthreads();

  for (int i = t; i < 3072; i += 256) {
    int r = i >> 6, c0 = (i & 63) * 8;
    float mu = smu[r], rs = srs[r];
    const uint16_t* src = (c0 < 256) ? (nm + r*LNM + c0)
                        : (c0 < 384) ? (xs + r*LX + (c0 - 256))
                                     : (qs + r*LQ + (c0 - 384));
    bf16x8 v = *(const bf16x8*)src;
    bf16x8 o;
    #pragma unroll
    for (int j = 0; j < 8; j++)
      o[j] = (short)f2bf((bf2f((uint16_t)v[j]) - mu) * rs * g2[c0+j] + be2[c0+j]);
    *(bf16x8*)(F + (r0 + r) * 512 + c0) = o;
  }
}

// ---------------- K4: out = relu(f @ W_s + b_s) ----------------
// 256x256 tile, 8 waves, BK=32, 3-slot LDS ring (96KB), stage-lead-2,
// counted vmcnt(4), single barrier/K-tile, conflict-free chunk-XOR swizzle,
// setprio around the 32-MFMA cluster.
__global__ __launch_bounds__(512, 2) void out_gemm(
    const uint16_t* __restrict__ F, const uint16_t* __restrict__ WsT,
    const float* __restrict__ b_s, float* __restrict__ OUT)
{
  __shared__ uint16_t lds[3][2][256*32];   // 96 KB: [slot][A/B][row*32 + chunk*8]
  int t = threadIdx.x;
  int lane = t & 63, wave = t >> 6;
  int wm = wave >> 2, wn = wave & 3;       // 2 x 4 wave grid
  int lr = lane & 15, lh = lane >> 4;

  // grid 512 = 128 m-blocks x 4 n-blocks; XCD-chunked, n-fastest
  int bid = blockIdx.x;
  int swz = (bid & 7) * 64 + (bid >> 3);
  size_t m0 = (size_t)(swz >> 2) * 256;
  int n0 = (swz & 3) * 256;

  // staging: thread covers LDS row t>>2 (0..127 per issue), chunk t&3;
  // global source chunk pre-swizzled: gch = (t&3) ^ ((row>>1)&3)
  int srow = t >> 2;
  int gch  = (t & 3) ^ ((t >> 3) & 3);
  const uint16_t* Ag = F   + (m0 + srow) * 3072 + gch * 8;
  const uint16_t* Bg = WsT + (size_t)(n0 + srow) * 3072 + gch * 8;

#define STAGE(s, tt) do {                                                    \
    int kk0 = (tt) * 32;                                                     \
    uint16_t* la = &lds[s][0][0];                                            \
    uint16_t* lb = &lds[s][1][0];                                            \
    gl2lds16(Ag + kk0,                    la + wave*512);                    \
    gl2lds16(Ag + (size_t)128*3072 + kk0, la + 4096 + wave*512);             \
    gl2lds16(Bg + kk0,                    lb + wave*512);                    \
    gl2lds16(Bg + (size_t)128*3072 + kk0, lb + 4096 + wave*512);             \
  } while(0)

  f32x4 acc[8][4] = {};
  int swch = (lh ^ ((lr >> 1) & 3)) * 8;   // swizzled read chunk (elems)

#define COMPUTE(s) do {                                                      \
    const uint16_t* As_ = &lds[s][0][0];                                     \
    const uint16_t* Bs_ = &lds[s][1][0];                                     \
    bf16x8 af[8], bfr[4];                                                    \
    _Pragma("unroll")                                                        \
    for (int i = 0; i < 8; i++)                                              \
      af[i]  = *(const bf16x8*)(As_ + (wm*128 + i*16 + lr)*32 + swch);       \
    _Pragma("unroll")                                                        \
    for (int j = 0; j < 4; j++)                                              \
      bfr[j] = *(const bf16x8*)(Bs_ + (wn*64 + j*16 + lr)*32 + swch);        \
    __builtin_amdgcn_s_setprio(1);                                           \
    _Pragma("unroll")                                                        \
    for (int i = 0; i < 8; i++)                                              \
      _Pragma("unroll")                                                      \
      for (int j = 0; j < 4; j++)                                            \
        acc[i][j] = __builtin_amdgcn_mfma_f32_16x16x32_bf16(af[i], bfr[j],   \
                                                            acc[i][j],0,0,0);\
    __builtin_amdgcn_s_setprio(0);                                           \
  } while(0)

  STAGE(0, 0);
  STAGE(1, 1);
  int ss = 2, sc = 0;                      // stage slot (tt+2)%3, compute slot tt%3
  for (int tt = 0; tt < 94; ++tt) {
    asm volatile("s_waitcnt vmcnt(4)" ::: "memory");   // tile tt landed
    __builtin_amdgcn_s_barrier();
    asm volatile("" ::: "memory");
    STAGE(ss, tt + 2);                    // writes slot (tt-1)%3: readers done
    COMPUTE(sc);
    ss = (ss == 2) ? 0 : ss + 1;
    sc = (sc == 2) ? 0 : sc + 1;
  }
  asm volatile("s_waitcnt vmcnt(4)" ::: "memory");     // tile 94 landed
  __builtin_amdgcn_s_barrier();
  asm volatile("" ::: "memory");
  COMPUTE(1);                              // 94 % 3
  asm volatile("s_waitcnt vmcnt(0)" ::: "memory");     // tile 95 landed
  __builtin_amdgcn_s_barrier();
  asm volatile("" ::: "memory");
  COMPUTE(2);                              // 95 % 3

#undef STAGE
#undef COMPUTE

  #pragma unroll
  for (int i = 0; i < 8; i++)
    #pragma unroll
    for (int j = 0; j < 4; j++) {
      int col = n0 + wn*64 + j*16 + lr;
      float bv = b_s[col];
      #pragma unroll
      for (int r = 0; r < 4; r++) {
        size_t row = m0 + wm*128 + i*16 + lh*4 + r;
        OUT[row * 1024 + col] = fmaxf(acc[i][j][r] + bv, 0.f);
      }
    }
}

extern "C" void kernel_launch(void* const* d_in, const int* in_sizes, int n_in,
                              void* d_out, int out_size, void* d_ws, size_t ws_size,
                              hipStream_t stream) {
  const float* x    = (const float*)d_in[0];
  const float* Wqkv = (const float*)d_in[1];
  const float* bqkv = (const float*)d_in[2];
  const float* g1   = (const float*)d_in[3];
  const float* be1  = (const float*)d_in[4];
  const float* Wfp  = (const float*)d_in[5];
  const float* bfp  = (const float*)d_in[6];
  const float* g2   = (const float*)d_in[7];
  const float* be2  = (const float*)d_in[8];
  const float* Ws   = (const float*)d_in[9];
  const float* bs   = (const float*)d_in[10];
  float* out = (float*)d_out;

  uint8_t* ws = (uint8_t*)d_ws;
  uint16_t* F     = (uint16_t*)(ws);                  // 32768x3072 bf16
  uint16_t* WqkvT = (uint16_t*)(ws + 201326592ull);
  uint16_t* WfpT  = (uint16_t*)(ws + 201424896ull);
  uint16_t* WsT   = (uint16_t*)(ws + 201555968ull);

  transpose_cvt<<<dim3(12, 4), 256, 0, stream>>>(Wqkv, WqkvT, 128, 384);
  transpose_cvt<<<dim3(8, 8), 256, 0, stream>>>(Wfp, WfpT, 256, 256);
  transpose_cvt<<<dim3(32, 96), 256, 0, stream>>>(Ws, WsT, 3072, 1024);
  fused_mid<<<dim3(4096), 256, 0, stream>>>(x, WqkvT, bqkv, g1, be1,
                                            WfpT, bfp, g2, be2, F);
  out_gemm<<<dim3(512), 512, 0, stream>>>(F, WsT, bs, out);
}